// Round 3
// baseline (428.170 us; speedup 1.0000x reference)
//
#include <hip/hip_runtime.h>

// Problem constants
#define B_ 4
#define N_ 4096
#define D_ 256
#define M_ (B_*N_)   // 16384

typedef _Float16 f16;
typedef _Float16 f16x8 __attribute__((ext_vector_type(8)));
typedef float    f32x4 __attribute__((ext_vector_type(4)));

// workspace layout (bytes)
#define QH_OFF   0u            // Qh:   16384*256*2 = 8388608
#define KH_OFF   8388608u      // Kh:   8388608
#define VT_OFF   16777216u     // Vt:   [4][256][4096] f16 = 8388608
#define WFCH_OFF 25165824u     // Wfch: 256*256*2 = 131072
#define WQS_OFF  25296896u     // Wqs:  256*512*2 = 262144 (hi|lo)
#define WKS_OFF  25559040u
#define WVS_OFF  25821184u
#define OP_OFF   26083328u     // Opart: f16 [4][16384][256] = 33554432
#define ML_OFF   59637760u     // Ml: f32 [4][16384][2] = 524288 -> total 60162048

// ---------------------------------------------------------------------------
// Kernel 1: weight conversion. z<3: W -> [col][0:256)=hi, [256:512)=lo f16.
// z==3: Wfc -> plain f16.
// ---------------------------------------------------------------------------
__global__ __launch_bounds__(256) void cvt_w(
    const float* __restrict__ Wq, const float* __restrict__ Wk,
    const float* __restrict__ Wv, const float* __restrict__ Wfc,
    f16* __restrict__ Wqs, f16* __restrict__ Wks, f16* __restrict__ Wvs,
    f16* __restrict__ Wfch)
{
    const int z = blockIdx.y;
    const float* W = (z==0) ? Wq : (z==1) ? Wk : (z==2) ? Wv : Wfc;
    int idx = (blockIdx.x * 256 + threadIdx.x) * 4;      // 0..65532
    float4 v = *(const float4*)(W + idx);
    union { ushort4 u4; f16 h[4]; } hi, lo;
    float vv[4] = {v.x, v.y, v.z, v.w};
    #pragma unroll
    for (int j = 0; j < 4; j++) {
        hi.h[j] = (f16)vv[j];
        lo.h[j] = (f16)(vv[j] - (float)hi.h[j]);
    }
    if (z == 3) {
        *(ushort4*)(Wfch + idx) = hi.u4;
    } else {
        f16* Ws = (z==0) ? Wqs : (z==1) ? Wks : Wvs;
        int col = idx >> 8, k = idx & 255;
        *(ushort4*)(Ws + col*512 + k)       = hi.u4;
        *(ushort4*)(Ws + col*512 + 256 + k) = lo.u4;
    }
}

// ---------------------------------------------------------------------------
// Kernel 2: QKV projection via f16 MFMA with hi/lo split (near-fp32 exact):
// (x_hi+x_lo)(W_hi+W_lo) accumulated in f32 -> error ~2^-22, logits stay clean.
// merge_fc pattern: no LDS, A-frags (x, converted on the fly) + B-frags (Ws)
// straight from global/L2. Block = 4 waves x 16 rows = 64 rows, all 256 cols.
// z==2 (V) scatters transposed to Vt[b][d][n] (L2 absorbs the 2B segments).
// ---------------------------------------------------------------------------
__global__ __launch_bounds__(256) void proj_kernel(
    const float* __restrict__ x,
    const f16* __restrict__ Wqs, const f16* __restrict__ Wks,
    const f16* __restrict__ Wvs,
    const float* __restrict__ bq, const float* __restrict__ bk,
    const float* __restrict__ bv,
    f16* __restrict__ Qh, f16* __restrict__ Kh, f16* __restrict__ Vt)
{
    const int z = blockIdx.y;
    const f16*   Ws   = (z==0) ? Wqs : (z==1) ? Wks : Wvs;
    const float* bias = (z==0) ? bq  : (z==1) ? bk  : bv;

    const int tid  = threadIdx.x;
    const int w    = tid >> 6;
    const int lane = tid & 63;
    const int l15  = lane & 15;
    const int q4   = lane >> 4;
    const int m0   = blockIdx.x * 64 + w * 16;
    const int rowA = m0 + l15;

    f32x4 acc[16];
    #pragma unroll
    for (int nt = 0; nt < 16; nt++) acc[nt] = (f32x4){0.f,0.f,0.f,0.f};

    #pragma unroll
    for (int dc = 0; dc < 8; dc++) {
        // A-frag: x row, k-chunk dc*32 + q4*8, split hi/lo on the fly
        float4 a0 = *(const float4*)(x + (size_t)rowA*256 + dc*32 + q4*8);
        float4 a1 = *(const float4*)(x + (size_t)rowA*256 + dc*32 + q4*8 + 4);
        float av[8] = {a0.x,a0.y,a0.z,a0.w,a1.x,a1.y,a1.z,a1.w};
        f16x8 ah, alo;
        #pragma unroll
        for (int j = 0; j < 8; j++) {
            ah[j]  = (f16)av[j];
            alo[j] = (f16)(av[j] - (float)ah[j]);
        }
        #pragma unroll
        for (int nt = 0; nt < 16; nt++) {
            const f16* bp = Ws + (size_t)(nt*16 + l15)*512 + dc*32 + q4*8;
            f16x8 bh = *(const f16x8*)bp;
            f16x8 bl = *(const f16x8*)(bp + 256);
            acc[nt] = __builtin_amdgcn_mfma_f32_16x16x32_f16(alo, bl, acc[nt], 0,0,0);
            acc[nt] = __builtin_amdgcn_mfma_f32_16x16x32_f16(ah,  bl, acc[nt], 0,0,0);
            acc[nt] = __builtin_amdgcn_mfma_f32_16x16x32_f16(alo, bh, acc[nt], 0,0,0);
            acc[nt] = __builtin_amdgcn_mfma_f32_16x16x32_f16(ah,  bh, acc[nt], 0,0,0);
        }
    }

    if (z < 2) {
        f16* outh = (z==0) ? Qh : Kh;
        #pragma unroll
        for (int nt = 0; nt < 16; nt++) {
            float bb = bias[nt*16 + l15];
            #pragma unroll
            for (int r = 0; r < 4; r++)
                outh[(size_t)(m0 + q4*4 + r)*256 + nt*16 + l15] = (f16)(acc[nt][r] + bb);
        }
    } else {
        const int b  = m0 >> 12;
        const int n0 = (m0 & 4095) + q4*4;
        #pragma unroll
        for (int nt = 0; nt < 16; nt++) {
            int e = nt*16 + l15;
            float bb = bias[e];
            #pragma unroll
            for (int r = 0; r < 4; r++)
                Vt[((size_t)b*256 + e)*4096 + n0 + r] = (f16)(acc[nt][r] + bb);
        }
    }
}

// ---------------------------------------------------------------------------
// Kernel 3: flash attention, fp16 MFMA, split-K x4.
// R3: (a) register-prefetch staging — next tile's global loads issued right
// after the fill-barrier so they fly during compute; vmcnt drain at the next
// fill is nearly free. (b) hysteresis online-softmax — running max only
// updated when tile max exceeds m+10 (P<=e^10 fits f16), so the al/exp/
// O-rescale chain runs a handful of times instead of ~24/32 iters.
// ---------------------------------------------------------------------------
#define MARGIN 10.0f
__global__ __launch_bounds__(256, 2) void attn_kernel(
    const f16* __restrict__ Qh, const f16* __restrict__ Kh,
    const f16* __restrict__ Vt,
    f16* __restrict__ Opart, float* __restrict__ Ml)
{
    __shared__ f16 Ks[32][264];     // [key][d]   528B stride
    __shared__ f16 VsT[256][40];    // [d][key]   80B stride
    __shared__ f16 Ps[4][32][40];   // per-wave P round-trip

    const int combo = blockIdx.x & 15;
    const int b   = combo >> 2;
    const int sp  = combo & 3;
    const int qt  = blockIdx.x >> 4;         // 0..31
    const int tid  = threadIdx.x;
    const int w    = tid >> 6;
    const int lane = tid & 63;
    const int l15  = lane & 15;
    const int q4   = lane >> 4;
    const int qbase = qt * 128 + w * 32;

    // Q fragments resident
    f16x8 qf[2][8];
    #pragma unroll
    for (int s = 0; s < 2; s++) {
        const f16* qp = Qh + ((size_t)(b*4096 + qbase + s*16 + l15)) * 256 + q4*8;
        #pragma unroll
        for (int dc = 0; dc < 8; dc++)
            qf[s][dc] = *(const f16x8*)(qp + dc*32);
    }

    f32x4 Oa[2][16];
    #pragma unroll
    for (int s = 0; s < 2; s++)
        #pragma unroll
        for (int nt = 0; nt < 16; nt++) Oa[s][nt] = (f32x4){0.f,0.f,0.f,0.f};
    float mo[2][4] = {{-3e38f,-3e38f,-3e38f,-3e38f},{-3e38f,-3e38f,-3e38f,-3e38f}};
    float ls[2][4] = {};

    const f16* kbase_p = Kh + ((size_t)(b*4096 + sp*1024)) * 256;
    const f16* vbase_p = Vt + ((size_t)b*256) * 4096 + sp*1024;
    int krow[4], kc[4];
    #pragma unroll
    for (int i = 0; i < 4; i++) { int idx = tid + i*256; krow[i] = idx >> 5; kc[i] = idx & 31; }
    const int vno = (tid & 3) * 8;
    const int vd0 = tid >> 2;

    // prologue: prefetch tile 0 into registers
    f16x8 kr[4], vr[4];
    #pragma unroll
    for (int i = 0; i < 4; i++) {
        kr[i] = *(const f16x8*)(kbase_p + (size_t)krow[i]*256 + kc[i]*8);
        vr[i] = *(const f16x8*)(vbase_p + (size_t)(vd0 + i*64)*4096 + vno);
    }

    for (int it = 0; it < 32; it++) {
        __syncthreads();                     // prev iter done reading LDS
        #pragma unroll
        for (int i = 0; i < 4; i++) {
            *(f16x8*)&Ks[krow[i]][kc[i]*8] = kr[i];
            *(f16x8*)&VsT[vd0 + i*64][vno] = vr[i];
        }
        __syncthreads();
        if (it + 1 < 32) {                   // prefetch next tile (flies during compute)
            const f16* kp = kbase_p + (size_t)(it+1)*32*256;
            const f16* vp = vbase_p + (it+1)*32;
            #pragma unroll
            for (int i = 0; i < 4; i++) {
                kr[i] = *(const f16x8*)(kp + (size_t)krow[i]*256 + kc[i]*8);
                vr[i] = *(const f16x8*)(vp + (size_t)(vd0 + i*64)*4096 + vno);
            }
        }

        // S = Q K^T : 32 q-rows x 32 keys, K B-frags reused by both subtiles
        f32x4 sa[2][2] = {{{0.f,0.f,0.f,0.f},{0.f,0.f,0.f,0.f}},
                          {{0.f,0.f,0.f,0.f},{0.f,0.f,0.f,0.f}}};
        #pragma unroll
        for (int dc = 0; dc < 8; dc++) {
            f16x8 b0 = *(const f16x8*)&Ks[l15][dc*32 + q4*8];
            f16x8 b1 = *(const f16x8*)&Ks[16 + l15][dc*32 + q4*8];
            sa[0][0] = __builtin_amdgcn_mfma_f32_16x16x32_f16(qf[0][dc], b0, sa[0][0], 0,0,0);
            sa[0][1] = __builtin_amdgcn_mfma_f32_16x16x32_f16(qf[0][dc], b1, sa[0][1], 0,0,0);
            sa[1][0] = __builtin_amdgcn_mfma_f32_16x16x32_f16(qf[1][dc], b0, sa[1][0], 0,0,0);
            sa[1][1] = __builtin_amdgcn_mfma_f32_16x16x32_f16(qf[1][dc], b1, sa[1][1], 0,0,0);
        }

        // hysteresis online softmax per subtile
        #pragma unroll
        for (int s = 0; s < 2; s++) {
            float tm[4];
            #pragma unroll
            for (int r = 0; r < 4; r++) tm[r] = fmaxf(sa[s][0][r], sa[s][1][r]);
            #pragma unroll
            for (int off = 1; off < 16; off <<= 1)
                #pragma unroll
                for (int r = 0; r < 4; r++)
                    tm[r] = fmaxf(tm[r], __shfl_xor(tm[r], off));
            bool trig = (tm[0] > mo[s][0] + MARGIN) | (tm[1] > mo[s][1] + MARGIN) |
                        (tm[2] > mo[s][2] + MARGIN) | (tm[3] > mo[s][3] + MARGIN);
            if (__any(trig)) {               // rare: rescale frame
                float al[4];
                #pragma unroll
                for (int r = 0; r < 4; r++) {
                    float mn = fmaxf(mo[s][r], tm[r]);
                    al[r] = __expf(mo[s][r] - mn);
                    mo[s][r] = mn;
                    ls[s][r] *= al[r];
                }
                #pragma unroll
                for (int nt = 0; nt < 16; nt++)
                    #pragma unroll
                    for (int r = 0; r < 4; r++)
                        Oa[s][nt][r] *= al[r];
            }
            float rs[4];
            #pragma unroll
            for (int r = 0; r < 4; r++) {
                float p0 = __expf(sa[s][0][r] - mo[s][r]);
                float p1 = __expf(sa[s][1][r] - mo[s][r]);
                rs[r] = p0 + p1;
                Ps[w][s*16 + q4*4 + r][l15]      = (f16)p0;
                Ps[w][s*16 + q4*4 + r][16 + l15] = (f16)p1;
            }
            #pragma unroll
            for (int off = 1; off < 16; off <<= 1)
                #pragma unroll
                for (int r = 0; r < 4; r++)
                    rs[r] += __shfl_xor(rs[r], off);
            #pragma unroll
            for (int r = 0; r < 4; r++) ls[s][r] += rs[r];
        }

        f16x8 ap0 = *(const f16x8*)&Ps[w][l15][q4*8];
        f16x8 ap1 = *(const f16x8*)&Ps[w][16 + l15][q4*8];

        #pragma unroll
        for (int nt = 0; nt < 16; nt++) {
            f16x8 bv = *(const f16x8*)&VsT[nt*16 + l15][q4*8];
            Oa[0][nt] = __builtin_amdgcn_mfma_f32_16x16x32_f16(ap0, bv, Oa[0][nt], 0,0,0);
            Oa[1][nt] = __builtin_amdgcn_mfma_f32_16x16x32_f16(ap1, bv, Oa[1][nt], 0,0,0);
        }
    }

    // epilogue: store NORMALIZED partial O (f16) + (m, l)
    #pragma unroll
    for (int s = 0; s < 2; s++) {
        float inv[4];
        #pragma unroll
        for (int r = 0; r < 4; r++) inv[r] = 1.0f / ls[s][r];
        f16* op = Opart + ((size_t)sp*M_ + b*4096 + qbase + s*16) * 256;
        #pragma unroll
        for (int nt = 0; nt < 16; nt++)
            #pragma unroll
            for (int r = 0; r < 4; r++)
                op[(size_t)(q4*4 + r) * 256 + nt*16 + l15] = (f16)(Oa[s][nt][r] * inv[r]);
        if (l15 == 0) {
            #pragma unroll
            for (int r = 0; r < 4; r++) {
                size_t mrow = (size_t)sp*M_ + b*4096 + qbase + s*16 + q4*4 + r;
                Ml[mrow*2]     = mo[s][r];
                Ml[mrow*2 + 1] = ls[s][r];
            }
        }
    }
}

// ---------------------------------------------------------------------------
// Kernel 4: merge 4 normalized k-quarter partials + FC (fp16 MFMA) + bias.
// ---------------------------------------------------------------------------
__global__ __launch_bounds__(256) void merge_fc_kernel(
    const f16* __restrict__ Opart, const float* __restrict__ Ml,
    const f16* __restrict__ Wfch, const float* __restrict__ bfc,
    float* __restrict__ out)
{
    const int tid  = threadIdx.x;
    const int w    = tid >> 6;
    const int lane = tid & 63;
    const int l15  = lane & 15;
    const int q4   = lane >> 4;
    const int m0   = blockIdx.x * 64 + w * 16;

    const int rowA = m0 + l15;
    float mv[4], lv[4];
    #pragma unroll
    for (int p = 0; p < 4; p++) {
        mv[p] = Ml[((size_t)p*M_ + rowA)*2];
        lv[p] = Ml[((size_t)p*M_ + rowA)*2 + 1];
    }
    float mm = fmaxf(fmaxf(mv[0], mv[1]), fmaxf(mv[2], mv[3]));
    float cw[4], den = 0.f;
    #pragma unroll
    for (int p = 0; p < 4; p++) { cw[p] = __expf(mv[p] - mm) * lv[p]; den += cw[p]; }
    float inv = 1.0f / den;
    #pragma unroll
    for (int p = 0; p < 4; p++) cw[p] *= inv;

    f16x8 af[8];
    #pragma unroll
    for (int dc = 0; dc < 8; dc++) {
        float v[8] = {};
        #pragma unroll
        for (int p = 0; p < 4; p++) {
            f16x8 o = *(const f16x8*)(Opart + ((size_t)p*M_ + rowA)*256 + q4*8 + dc*32);
            #pragma unroll
            for (int j = 0; j < 8; j++) v[j] += cw[p] * (float)o[j];
        }
        f16x8 h;
        #pragma unroll
        for (int j = 0; j < 8; j++) h[j] = (f16)v[j];
        af[dc] = h;
    }

    f32x4 acc[16];
    #pragma unroll
    for (int nt = 0; nt < 16; nt++) acc[nt] = (f32x4){0.f,0.f,0.f,0.f};
    #pragma unroll
    for (int dc = 0; dc < 8; dc++) {
        #pragma unroll
        for (int nt = 0; nt < 16; nt++) {
            f16x8 bf = *(const f16x8*)(Wfch + (size_t)(nt*16 + l15)*256 + dc*32 + q4*8);
            acc[nt] = __builtin_amdgcn_mfma_f32_16x16x32_f16(af[dc], bf, acc[nt], 0,0,0);
        }
    }
    #pragma unroll
    for (int nt = 0; nt < 16; nt++) {
        float bias = bfc[nt*16 + l15];
        #pragma unroll
        for (int r = 0; r < 4; r++)
            out[(size_t)(m0 + q4*4 + r) * 256 + nt*16 + l15] = acc[nt][r] + bias;
    }
}

// ---------------------------------------------------------------------------
extern "C" void kernel_launch(void* const* d_in, const int* in_sizes, int n_in,
                              void* d_out, int out_size, void* d_ws, size_t ws_size,
                              hipStream_t stream)
{
    const float* x   = (const float*)d_in[0];
    const float* Wq  = (const float*)d_in[1];
    const float* bq  = (const float*)d_in[2];
    const float* Wk  = (const float*)d_in[3];
    const float* bk  = (const float*)d_in[4];
    const float* Wv  = (const float*)d_in[5];
    const float* bv  = (const float*)d_in[6];
    const float* Wfc = (const float*)d_in[7];
    const float* bfc = (const float*)d_in[8];
    float* out = (float*)d_out;

    char* ws = (char*)d_ws;
    f16*   Qh    = (f16*)(ws + QH_OFF);
    f16*   Kh    = (f16*)(ws + KH_OFF);
    f16*   Vt    = (f16*)(ws + VT_OFF);
    f16*   Wfch  = (f16*)(ws + WFCH_OFF);
    f16*   Wqs   = (f16*)(ws + WQS_OFF);
    f16*   Wks   = (f16*)(ws + WKS_OFF);
    f16*   Wvs   = (f16*)(ws + WVS_OFF);
    f16*   Opart = (f16*)(ws + OP_OFF);
    float* Ml    = (float*)(ws + ML_OFF);

    cvt_w<<<dim3(64, 4), 256, 0, stream>>>(Wq, Wk, Wv, Wfc, Wqs, Wks, Wvs, Wfch);
    proj_kernel<<<dim3(256, 3), 256, 0, stream>>>(x, Wqs, Wks, Wvs, bq, bk, bv, Qh, Kh, Vt);
    attn_kernel<<<512, 256, 0, stream>>>(Qh, Kh, Vt, Opart, Ml);
    merge_fc_kernel<<<256, 256, 0, stream>>>(Opart, Ml, Wfch, bfc, out);
}

// Round 4
// 338.012 us; speedup vs baseline: 1.2667x; 1.2667x over previous
//
#include <hip/hip_runtime.h>
#include <stdint.h>

// Problem constants
#define B_ 4
#define N_ 4096
#define D_ 256
#define M_ (B_*N_)   // 16384

typedef _Float16 f16;
typedef _Float16 f16x8 __attribute__((ext_vector_type(8)));
typedef float    f32x4 __attribute__((ext_vector_type(4)));

// workspace layout (bytes)
#define QH_OFF   0u            // Qh:   16384*256*2 = 8388608
#define KH_OFF   8388608u      // Kh:   8388608 (PRE-SWIZZLED, see proj)
#define VT_OFF   16777216u     // Vt:   [4][256][4096] f16 = 8388608
#define WFCH_OFF 25165824u     // Wfch: 256*256*2 = 131072
#define WQS_OFF  25296896u     // Wqs:  256*512*2 = 262144 (hi|lo)
#define WKS_OFF  25559040u
#define WVS_OFF  25821184u
#define OP_OFF   26083328u     // Opart: f16 [4][16384][256] = 33554432
#define ML_OFF   59637760u     // Ml: f32 [4][16384][2] = 524288 -> total 60162048

typedef __attribute__((address_space(3))) uint32_t lds_u32;
typedef __attribute__((address_space(1))) const uint32_t g_u32;

// async global->LDS, 16B per lane, LDS dest = uniform base + lane*16
__device__ __forceinline__ void stage16(const f16* g, f16* lbase) {
    __builtin_amdgcn_global_load_lds((g_u32*)g, (lds_u32*)lbase, 16, 0, 0);
}

// ---------------------------------------------------------------------------
// Kernel 1: weight conversion. z<3: W -> [col][0:256)=hi, [256:512)=lo f16.
// z==3: Wfc -> plain f16.
// ---------------------------------------------------------------------------
__global__ __launch_bounds__(256) void cvt_w(
    const float* __restrict__ Wq, const float* __restrict__ Wk,
    const float* __restrict__ Wv, const float* __restrict__ Wfc,
    f16* __restrict__ Wqs, f16* __restrict__ Wks, f16* __restrict__ Wvs,
    f16* __restrict__ Wfch)
{
    const int z = blockIdx.y;
    const float* W = (z==0) ? Wq : (z==1) ? Wk : (z==2) ? Wv : Wfc;
    int idx = (blockIdx.x * 256 + threadIdx.x) * 4;      // 0..65532
    float4 v = *(const float4*)(W + idx);
    union { ushort4 u4; f16 h[4]; } hi, lo;
    float vv[4] = {v.x, v.y, v.z, v.w};
    #pragma unroll
    for (int j = 0; j < 4; j++) {
        hi.h[j] = (f16)vv[j];
        lo.h[j] = (f16)(vv[j] - (float)hi.h[j]);
    }
    if (z == 3) {
        *(ushort4*)(Wfch + idx) = hi.u4;
    } else {
        f16* Ws = (z==0) ? Wqs : (z==1) ? Wks : Wvs;
        int col = idx >> 8, k = idx & 255;
        *(ushort4*)(Ws + col*512 + k)       = hi.u4;
        *(ushort4*)(Ws + col*512 + 256 + k) = lo.u4;
    }
}

// ---------------------------------------------------------------------------
// Kernel 2: QKV projection via f16 MFMA with hi/lo split (near-fp32 exact).
// 3-term: ah*bh + ah*bl + alo*bh (alo*bl ~2^-22, dropped).
// z==1 (K) writes Kh PRE-SWIZZLED for attn's global_load_lds staging:
//   element (key m, col e) -> Kh[m*256 + ((e>>3) ^ (m&7))*8 + (e&7)]
// z==2 (V) scatters transposed to Vt[b][d][n].
// ---------------------------------------------------------------------------
__global__ __launch_bounds__(256) void proj_kernel(
    const float* __restrict__ x,
    const f16* __restrict__ Wqs, const f16* __restrict__ Wks,
    const f16* __restrict__ Wvs,
    const float* __restrict__ bq, const float* __restrict__ bk,
    const float* __restrict__ bv,
    f16* __restrict__ Qh, f16* __restrict__ Kh, f16* __restrict__ Vt)
{
    const int z = blockIdx.y;
    const f16*   Ws   = (z==0) ? Wqs : (z==1) ? Wks : Wvs;
    const float* bias = (z==0) ? bq  : (z==1) ? bk  : bv;

    const int tid  = threadIdx.x;
    const int w    = tid >> 6;
    const int lane = tid & 63;
    const int l15  = lane & 15;
    const int q4   = lane >> 4;
    const int m0   = blockIdx.x * 64 + w * 16;
    const int rowA = m0 + l15;

    f32x4 acc[16];
    #pragma unroll
    for (int nt = 0; nt < 16; nt++) acc[nt] = (f32x4){0.f,0.f,0.f,0.f};

    #pragma unroll
    for (int dc = 0; dc < 8; dc++) {
        float4 a0 = *(const float4*)(x + (size_t)rowA*256 + dc*32 + q4*8);
        float4 a1 = *(const float4*)(x + (size_t)rowA*256 + dc*32 + q4*8 + 4);
        float av[8] = {a0.x,a0.y,a0.z,a0.w,a1.x,a1.y,a1.z,a1.w};
        f16x8 ah, alo;
        #pragma unroll
        for (int j = 0; j < 8; j++) {
            ah[j]  = (f16)av[j];
            alo[j] = (f16)(av[j] - (float)ah[j]);
        }
        #pragma unroll
        for (int nt = 0; nt < 16; nt++) {
            const f16* bp = Ws + (size_t)(nt*16 + l15)*512 + dc*32 + q4*8;
            f16x8 bh = *(const f16x8*)bp;
            f16x8 bl = *(const f16x8*)(bp + 256);
            acc[nt] = __builtin_amdgcn_mfma_f32_16x16x32_f16(ah,  bl, acc[nt], 0,0,0);
            acc[nt] = __builtin_amdgcn_mfma_f32_16x16x32_f16(alo, bh, acc[nt], 0,0,0);
            acc[nt] = __builtin_amdgcn_mfma_f32_16x16x32_f16(ah,  bh, acc[nt], 0,0,0);
        }
    }

    if (z == 0) {
        #pragma unroll
        for (int nt = 0; nt < 16; nt++) {
            float bb = bias[nt*16 + l15];
            #pragma unroll
            for (int r = 0; r < 4; r++)
                Qh[(size_t)(m0 + q4*4 + r)*256 + nt*16 + l15] = (f16)(acc[nt][r] + bb);
        }
    } else if (z == 1) {
        // swizzled Kh write
        const int cbase = (l15 >> 3);       // within-chunk-pair bit of e>>3
        const int j     = l15 & 7;
        #pragma unroll
        for (int nt = 0; nt < 16; nt++) {
            float bb = bias[nt*16 + l15];
            int c = nt*2 + cbase;           // e>>3
            #pragma unroll
            for (int r = 0; r < 4; r++) {
                int m = m0 + q4*4 + r;
                Kh[(size_t)m*256 + (size_t)((c ^ (m & 7)) << 3) + j] = (f16)(acc[nt][r] + bb);
            }
        }
    } else {
        const int b  = m0 >> 12;
        const int n0 = (m0 & 4095) + q4*4;
        #pragma unroll
        for (int nt = 0; nt < 16; nt++) {
            int e = nt*16 + l15;
            float bb = bias[e];
            #pragma unroll
            for (int r = 0; r < 4; r++)
                Vt[((size_t)b*256 + e)*4096 + n0 + r] = (f16)(acc[nt][r] + bb);
        }
    }
}

// ---------------------------------------------------------------------------
// Kernel 3: flash attention, fp16 MFMA, split-K x4.
// R4: (a) K staged via global_load_lds into a DOUBLE-BUFFERED unpadded
// Ks[2][32][256] (no VGPR round-trip -> no spill); Kh is pre-swizzled so the
// linear DMA image gives 2-way-conflict-free reads (chunk ^ row&7).
// The t+1 DMA is issued right after barrier1 and drains at barrier2, hidden
// behind S+softmax. (b) shuffle-free hysteresis softmax: per-lane trigger
// compare + __any (no per-iter max reduce), per-lane deferred l-sum reduced
// once in the epilogue, O-rescale only on trigger.
// ---------------------------------------------------------------------------
#define MARGIN 10.0f
__global__ __launch_bounds__(256, 2) void attn_kernel(
    const f16* __restrict__ Qh, const f16* __restrict__ Kh,
    const f16* __restrict__ Vt,
    f16* __restrict__ Opart, float* __restrict__ Ml)
{
    __shared__ __align__(16) f16 Ks[2][32][256];  // dbuf, unpadded (DMA image)
    __shared__ __align__(16) f16 VsT[256][40];    // [d][key] 80B stride
    __shared__ __align__(16) f16 Ps[4][32][40];   // per-wave P round-trip

    const int combo = blockIdx.x & 15;
    const int b   = combo >> 2;
    const int sp  = combo & 3;
    const int qt  = blockIdx.x >> 4;         // 0..31
    const int tid  = threadIdx.x;
    const int w    = tid >> 6;
    const int lane = tid & 63;
    const int l15  = lane & 15;
    const int q4   = lane >> 4;
    const int qbase = qt * 128 + w * 32;
    const int sw   = l15 & 7;                // K read swizzle

    // Q fragments resident
    f16x8 qf[2][8];
    #pragma unroll
    for (int s = 0; s < 2; s++) {
        const f16* qp = Qh + ((size_t)(b*4096 + qbase + s*16 + l15)) * 256 + q4*8;
        #pragma unroll
        for (int dc = 0; dc < 8; dc++)
            qf[s][dc] = *(const f16x8*)(qp + dc*32);
    }

    f32x4 Oa[2][16];
    #pragma unroll
    for (int s = 0; s < 2; s++)
        #pragma unroll
        for (int nt = 0; nt < 16; nt++) Oa[s][nt] = (f32x4){0.f,0.f,0.f,0.f};
    float mo[2][4] = {{-3e38f,-3e38f,-3e38f,-3e38f},{-3e38f,-3e38f,-3e38f,-3e38f}};
    float ls[2][4] = {};                     // PER-LANE partial l (2 cols/lane)

    const f16* kg0 = Kh + ((size_t)(b*4096 + sp*1024)) * 256;  // swizzled layout
    const f16* vbase_p = Vt + ((size_t)b*256) * 4096 + sp*1024;
    const int vno = (tid & 3) * 8;
    const int vd0 = tid >> 2;

    // prologue: DMA tile 0 into buffer 0 (wave w stages rows w*8..w*8+7)
    {
        const f16* g = kg0 + (size_t)(w*8)*256 + lane*8;
        f16* l = &Ks[0][w*8][0];
        #pragma unroll
        for (int i = 0; i < 4; i++)
            stage16(g + i*512, l + i*512);
    }

    for (int it = 0; it < 32; it++) {
        const int cur = it & 1;
        __syncthreads();                     // prev iter done reading LDS; K DMA drained
        // issue next K tile DMA into the other buffer (drains at barrier2)
        if (it + 1 < 32) {
            const f16* g = kg0 + (size_t)(it+1)*32*256 + (size_t)(w*8)*256 + lane*8;
            f16* l = &Ks[cur ^ 1][w*8][0];
            #pragma unroll
            for (int i = 0; i < 4; i++)
                stage16(g + i*512, l + i*512);
        }
        // V tile: reg round-trip (short-lived), loads fly during S-phase
        f16x8 vr[4];
        {
            const f16* vp = vbase_p + it*32;
            #pragma unroll
            for (int i = 0; i < 4; i++)
                vr[i] = *(const f16x8*)(vp + (size_t)(vd0 + i*64)*4096 + vno);
        }

        // S = Q K^T from Ks[cur] (filled last iter, no wait)
        const f16* kr0 = &Ks[cur][l15][0];
        const f16* kr1 = &Ks[cur][16 + l15][0];
        f32x4 sa[2][2] = {{{0.f,0.f,0.f,0.f},{0.f,0.f,0.f,0.f}},
                          {{0.f,0.f,0.f,0.f},{0.f,0.f,0.f,0.f}}};
        #pragma unroll
        for (int dc = 0; dc < 8; dc++) {
            int c = ((dc*4 + q4) ^ sw) << 3;
            f16x8 b0 = *(const f16x8*)(kr0 + c);
            f16x8 b1 = *(const f16x8*)(kr1 + c);
            sa[0][0] = __builtin_amdgcn_mfma_f32_16x16x32_f16(qf[0][dc], b0, sa[0][0], 0,0,0);
            sa[0][1] = __builtin_amdgcn_mfma_f32_16x16x32_f16(qf[0][dc], b1, sa[0][1], 0,0,0);
            sa[1][0] = __builtin_amdgcn_mfma_f32_16x16x32_f16(qf[1][dc], b0, sa[1][0], 0,0,0);
            sa[1][1] = __builtin_amdgcn_mfma_f32_16x16x32_f16(qf[1][dc], b1, sa[1][1], 0,0,0);
        }

        // shuffle-free hysteresis softmax per subtile
        #pragma unroll
        for (int s = 0; s < 2; s++) {
            float tm[4];
            bool trig = false;
            #pragma unroll
            for (int r = 0; r < 4; r++) {
                tm[r] = fmaxf(sa[s][0][r], sa[s][1][r]);
                trig |= (tm[r] > mo[s][r] + MARGIN);
            }
            if (__any(trig)) {               // rare frame-rescale path
                #pragma unroll
                for (int off = 1; off < 16; off <<= 1)
                    #pragma unroll
                    for (int r = 0; r < 4; r++)
                        tm[r] = fmaxf(tm[r], __shfl_xor(tm[r], off));
                float al[4];
                #pragma unroll
                for (int r = 0; r < 4; r++) {
                    float mn = fmaxf(mo[s][r], tm[r]);
                    al[r] = __expf(mo[s][r] - mn);
                    mo[s][r] = mn;
                    ls[s][r] *= al[r];
                }
                #pragma unroll
                for (int nt = 0; nt < 16; nt++)
                    #pragma unroll
                    for (int r = 0; r < 4; r++)
                        Oa[s][nt][r] *= al[r];
            }
            #pragma unroll
            for (int r = 0; r < 4; r++) {
                float p0 = __expf(sa[s][0][r] - mo[s][r]);
                float p1 = __expf(sa[s][1][r] - mo[s][r]);
                ls[s][r] += p0 + p1;         // per-lane partial; reduced in epilogue
                Ps[w][s*16 + q4*4 + r][l15]      = (f16)p0;
                Ps[w][s*16 + q4*4 + r][16 + l15] = (f16)p1;
            }
        }

        // write V tile to LDS (waits its vmcnt), then barrier2 (drains K DMA)
        #pragma unroll
        for (int i = 0; i < 4; i++)
            *(f16x8*)&VsT[vd0 + i*64][vno] = vr[i];
        __syncthreads();

        f16x8 ap0 = *(const f16x8*)&Ps[w][l15][q4*8];
        f16x8 ap1 = *(const f16x8*)&Ps[w][16 + l15][q4*8];

        #pragma unroll
        for (int nt = 0; nt < 16; nt++) {
            f16x8 bv = *(const f16x8*)&VsT[nt*16 + l15][q4*8];
            Oa[0][nt] = __builtin_amdgcn_mfma_f32_16x16x32_f16(ap0, bv, Oa[0][nt], 0,0,0);
            Oa[1][nt] = __builtin_amdgcn_mfma_f32_16x16x32_f16(ap1, bv, Oa[1][nt], 0,0,0);
        }
    }

    // epilogue: reduce per-lane l across the 16-lane row group (once), then
    // store NORMALIZED partial O (f16) + (m, l)
    #pragma unroll
    for (int s = 0; s < 2; s++) {
        float lsum[4];
        #pragma unroll
        for (int r = 0; r < 4; r++) lsum[r] = ls[s][r];
        #pragma unroll
        for (int off = 1; off < 16; off <<= 1)
            #pragma unroll
            for (int r = 0; r < 4; r++)
                lsum[r] += __shfl_xor(lsum[r], off);
        float inv[4];
        #pragma unroll
        for (int r = 0; r < 4; r++) inv[r] = 1.0f / lsum[r];
        f16* op = Opart + ((size_t)sp*M_ + b*4096 + qbase + s*16) * 256;
        #pragma unroll
        for (int nt = 0; nt < 16; nt++)
            #pragma unroll
            for (int r = 0; r < 4; r++)
                op[(size_t)(q4*4 + r) * 256 + nt*16 + l15] = (f16)(Oa[s][nt][r] * inv[r]);
        if (l15 == 0) {
            #pragma unroll
            for (int r = 0; r < 4; r++) {
                size_t mrow = (size_t)sp*M_ + b*4096 + qbase + s*16 + q4*4 + r;
                Ml[mrow*2]     = mo[s][r];
                Ml[mrow*2 + 1] = lsum[r];
            }
        }
    }
}

// ---------------------------------------------------------------------------
// Kernel 4: merge 4 normalized k-quarter partials + FC (fp16 MFMA) + bias.
// ---------------------------------------------------------------------------
__global__ __launch_bounds__(256) void merge_fc_kernel(
    const f16* __restrict__ Opart, const float* __restrict__ Ml,
    const f16* __restrict__ Wfch, const float* __restrict__ bfc,
    float* __restrict__ out)
{
    const int tid  = threadIdx.x;
    const int w    = tid >> 6;
    const int lane = tid & 63;
    const int l15  = lane & 15;
    const int q4   = lane >> 4;
    const int m0   = blockIdx.x * 64 + w * 16;

    const int rowA = m0 + l15;
    float mv[4], lv[4];
    #pragma unroll
    for (int p = 0; p < 4; p++) {
        mv[p] = Ml[((size_t)p*M_ + rowA)*2];
        lv[p] = Ml[((size_t)p*M_ + rowA)*2 + 1];
    }
    float mm = fmaxf(fmaxf(mv[0], mv[1]), fmaxf(mv[2], mv[3]));
    float cw[4], den = 0.f;
    #pragma unroll
    for (int p = 0; p < 4; p++) { cw[p] = __expf(mv[p] - mm) * lv[p]; den += cw[p]; }
    float inv = 1.0f / den;
    #pragma unroll
    for (int p = 0; p < 4; p++) cw[p] *= inv;

    f16x8 af[8];
    #pragma unroll
    for (int dc = 0; dc < 8; dc++) {
        float v[8] = {};
        #pragma unroll
        for (int p = 0; p < 4; p++) {
            f16x8 o = *(const f16x8*)(Opart + ((size_t)p*M_ + rowA)*256 + q4*8 + dc*32);
            #pragma unroll
            for (int j = 0; j < 8; j++) v[j] += cw[p] * (float)o[j];
        }
        f16x8 h;
        #pragma unroll
        for (int j = 0; j < 8; j++) h[j] = (f16)v[j];
        af[dc] = h;
    }

    f32x4 acc[16];
    #pragma unroll
    for (int nt = 0; nt < 16; nt++) acc[nt] = (f32x4){0.f,0.f,0.f,0.f};
    #pragma unroll
    for (int dc = 0; dc < 8; dc++) {
        #pragma unroll
        for (int nt = 0; nt < 16; nt++) {
            f16x8 bf = *(const f16x8*)(Wfch + (size_t)(nt*16 + l15)*256 + dc*32 + q4*8);
            acc[nt] = __builtin_amdgcn_mfma_f32_16x16x32_f16(af[dc], bf, acc[nt], 0,0,0);
        }
    }
    #pragma unroll
    for (int nt = 0; nt < 16; nt++) {
        float bias = bfc[nt*16 + l15];
        #pragma unroll
        for (int r = 0; r < 4; r++)
            out[(size_t)(m0 + q4*4 + r) * 256 + nt*16 + l15] = acc[nt][r] + bias;
    }
}

// ---------------------------------------------------------------------------
extern "C" void kernel_launch(void* const* d_in, const int* in_sizes, int n_in,
                              void* d_out, int out_size, void* d_ws, size_t ws_size,
                              hipStream_t stream)
{
    const float* x   = (const float*)d_in[0];
    const float* Wq  = (const float*)d_in[1];
    const float* bq  = (const float*)d_in[2];
    const float* Wk  = (const float*)d_in[3];
    const float* bk  = (const float*)d_in[4];
    const float* Wv  = (const float*)d_in[5];
    const float* bv  = (const float*)d_in[6];
    const float* Wfc = (const float*)d_in[7];
    const float* bfc = (const float*)d_in[8];
    float* out = (float*)d_out;

    char* ws = (char*)d_ws;
    f16*   Qh    = (f16*)(ws + QH_OFF);
    f16*   Kh    = (f16*)(ws + KH_OFF);
    f16*   Vt    = (f16*)(ws + VT_OFF);
    f16*   Wfch  = (f16*)(ws + WFCH_OFF);
    f16*   Wqs   = (f16*)(ws + WQS_OFF);
    f16*   Wks   = (f16*)(ws + WKS_OFF);
    f16*   Wvs   = (f16*)(ws + WVS_OFF);
    f16*   Opart = (f16*)(ws + OP_OFF);
    float* Ml    = (float*)(ws + ML_OFF);

    cvt_w<<<dim3(64, 4), 256, 0, stream>>>(Wq, Wk, Wv, Wfc, Wqs, Wks, Wvs, Wfch);
    proj_kernel<<<dim3(256, 3), 256, 0, stream>>>(x, Wqs, Wks, Wvs, bq, bk, bv, Qh, Kh, Vt);
    attn_kernel<<<512, 256, 0, stream>>>(Qh, Kh, Vt, Opart, Ml);
    merge_fc_kernel<<<256, 256, 0, stream>>>(Opart, Ml, Wfch, bfc, out);
}

// Round 5
// 318.725 us; speedup vs baseline: 1.3434x; 1.0605x over previous
//
#include <hip/hip_runtime.h>
#include <stdint.h>

// Problem constants
#define B_ 4
#define N_ 4096
#define D_ 256
#define M_ (B_*N_)   // 16384

typedef _Float16 f16;
typedef _Float16 f16x8 __attribute__((ext_vector_type(8)));
typedef float    f32x4 __attribute__((ext_vector_type(4)));

// workspace layout (bytes)
#define QH_OFF   0u            // Qh:   16384*256*2 = 8388608
#define KH_OFF   8388608u      // Kh:   8388608 (PRE-SWIZZLED, see proj)
#define VT_OFF   16777216u     // Vt:   [4][256][4096] f16 = 8388608
#define WFCH_OFF 25165824u     // Wfch: 256*256*2 = 131072
#define WQS_OFF  25296896u     // Wqs:  256*512*2 = 262144 (hi|lo)
#define WKS_OFF  25559040u
#define WVS_OFF  25821184u
#define OP_OFF   26083328u     // Opart: f16 [4][16384][256] = 33554432
#define ML_OFF   59637760u     // Ml: f32 [4][16384][2] = 524288 -> total 60162048

typedef __attribute__((address_space(3))) uint32_t lds_u32;
typedef __attribute__((address_space(1))) const uint32_t g_u32;

// async global->LDS, 16B per lane, LDS dest = uniform base + lane*16
__device__ __forceinline__ void stage16(const f16* g, f16* lbase) {
    __builtin_amdgcn_global_load_lds((g_u32*)g, (lds_u32*)lbase, 16, 0, 0);
}

// ---------------------------------------------------------------------------
// Kernel 1: weight conversion. z<3: W -> [col][0:256)=hi, [256:512)=lo f16.
// z==3: Wfc -> plain f16.
// ---------------------------------------------------------------------------
__global__ __launch_bounds__(256) void cvt_w(
    const float* __restrict__ Wq, const float* __restrict__ Wk,
    const float* __restrict__ Wv, const float* __restrict__ Wfc,
    f16* __restrict__ Wqs, f16* __restrict__ Wks, f16* __restrict__ Wvs,
    f16* __restrict__ Wfch)
{
    const int z = blockIdx.y;
    const float* W = (z==0) ? Wq : (z==1) ? Wk : (z==2) ? Wv : Wfc;
    int idx = (blockIdx.x * 256 + threadIdx.x) * 4;      // 0..65532
    float4 v = *(const float4*)(W + idx);
    union { ushort4 u4; f16 h[4]; } hi, lo;
    float vv[4] = {v.x, v.y, v.z, v.w};
    #pragma unroll
    for (int j = 0; j < 4; j++) {
        hi.h[j] = (f16)vv[j];
        lo.h[j] = (f16)(vv[j] - (float)hi.h[j]);
    }
    if (z == 3) {
        *(ushort4*)(Wfch + idx) = hi.u4;
    } else {
        f16* Ws = (z==0) ? Wqs : (z==1) ? Wks : Wvs;
        int col = idx >> 8, k = idx & 255;
        *(ushort4*)(Ws + col*512 + k)       = hi.u4;
        *(ushort4*)(Ws + col*512 + 256 + k) = lo.u4;
    }
}

// ---------------------------------------------------------------------------
// Kernel 2: QKV projection via f16 MFMA with hi/lo split (near-fp32 exact).
// 3-term: ah*bh + ah*bl + alo*bh.
// z==1 (K) writes Kh PRE-SWIZZLED for attn's global_load_lds staging:
//   element (key m, col e) -> Kh[m*256 + ((e>>3) ^ (m&7))*8 + (e&7)]
// z==2 (V) scatters transposed to Vt[b][d][n].
// ---------------------------------------------------------------------------
__global__ __launch_bounds__(256) void proj_kernel(
    const float* __restrict__ x,
    const f16* __restrict__ Wqs, const f16* __restrict__ Wks,
    const f16* __restrict__ Wvs,
    const float* __restrict__ bq, const float* __restrict__ bk,
    const float* __restrict__ bv,
    f16* __restrict__ Qh, f16* __restrict__ Kh, f16* __restrict__ Vt)
{
    const int z = blockIdx.y;
    const f16*   Ws   = (z==0) ? Wqs : (z==1) ? Wks : Wvs;
    const float* bias = (z==0) ? bq  : (z==1) ? bk  : bv;

    const int tid  = threadIdx.x;
    const int w    = tid >> 6;
    const int lane = tid & 63;
    const int l15  = lane & 15;
    const int q4   = lane >> 4;
    const int m0   = blockIdx.x * 64 + w * 16;
    const int rowA = m0 + l15;

    f32x4 acc[16];
    #pragma unroll
    for (int nt = 0; nt < 16; nt++) acc[nt] = (f32x4){0.f,0.f,0.f,0.f};

    #pragma unroll
    for (int dc = 0; dc < 8; dc++) {
        float4 a0 = *(const float4*)(x + (size_t)rowA*256 + dc*32 + q4*8);
        float4 a1 = *(const float4*)(x + (size_t)rowA*256 + dc*32 + q4*8 + 4);
        float av[8] = {a0.x,a0.y,a0.z,a0.w,a1.x,a1.y,a1.z,a1.w};
        f16x8 ah, alo;
        #pragma unroll
        for (int j = 0; j < 8; j++) {
            ah[j]  = (f16)av[j];
            alo[j] = (f16)(av[j] - (float)ah[j]);
        }
        #pragma unroll
        for (int nt = 0; nt < 16; nt++) {
            const f16* bp = Ws + (size_t)(nt*16 + l15)*512 + dc*32 + q4*8;
            f16x8 bh = *(const f16x8*)bp;
            f16x8 bl = *(const f16x8*)(bp + 256);
            acc[nt] = __builtin_amdgcn_mfma_f32_16x16x32_f16(ah,  bl, acc[nt], 0,0,0);
            acc[nt] = __builtin_amdgcn_mfma_f32_16x16x32_f16(alo, bh, acc[nt], 0,0,0);
            acc[nt] = __builtin_amdgcn_mfma_f32_16x16x32_f16(ah,  bh, acc[nt], 0,0,0);
        }
    }

    if (z == 0) {
        #pragma unroll
        for (int nt = 0; nt < 16; nt++) {
            float bb = bias[nt*16 + l15];
            #pragma unroll
            for (int r = 0; r < 4; r++)
                Qh[(size_t)(m0 + q4*4 + r)*256 + nt*16 + l15] = (f16)(acc[nt][r] + bb);
        }
    } else if (z == 1) {
        const int cbase = (l15 >> 3);
        const int j     = l15 & 7;
        #pragma unroll
        for (int nt = 0; nt < 16; nt++) {
            float bb = bias[nt*16 + l15];
            int c = nt*2 + cbase;
            #pragma unroll
            for (int r = 0; r < 4; r++) {
                int m = m0 + q4*4 + r;
                Kh[(size_t)m*256 + (size_t)((c ^ (m & 7)) << 3) + j] = (f16)(acc[nt][r] + bb);
            }
        }
    } else {
        const int b  = m0 >> 12;
        const int n0 = (m0 & 4095) + q4*4;
        #pragma unroll
        for (int nt = 0; nt < 16; nt++) {
            int e = nt*16 + l15;
            float bb = bias[e];
            #pragma unroll
            for (int r = 0; r < 4; r++)
                Vt[((size_t)b*256 + e)*4096 + n0 + r] = (f16)(acc[nt][r] + bb);
        }
    }
}

// ---------------------------------------------------------------------------
// Kernel 3: flash attention, fp16 MFMA, split-K x4.
// R5: single barrier per k-tile. K AND V staged via global_load_lds into
// double buffers (V uses a DMA-image permutation so the unpadded layout
// reads bank-uniform: slot = d*4 + (q4 ^ (d&3))). Per iter t:
//   barrier (drains K(t), V(t-1) DMAs) -> issue K(t+1),V(t) DMAs ->
//   S(t) interleaved with PV(t-1) (64 independent MFMAs) -> softmax(t).
// PV deferred one iteration hides the P LDS round-trip.
// ---------------------------------------------------------------------------
#define MARGIN 10.0f
__global__ __launch_bounds__(256, 2) void attn_kernel(
    const f16* __restrict__ Qh, const f16* __restrict__ Kh,
    const f16* __restrict__ Vt,
    f16* __restrict__ Opart, float* __restrict__ Ml)
{
    __shared__ __align__(16) f16 Ks[2][8192];     // [key5][chunk5^key&7][8]
    __shared__ __align__(16) f16 Vs[2][8192];     // slot = d*4 + (c ^ (d&3))
    __shared__ __align__(16) f16 Ps[4][32][40];   // per-wave P round-trip

    const int combo = blockIdx.x & 15;
    const int b   = combo >> 2;
    const int sp  = combo & 3;
    const int qt  = blockIdx.x >> 4;         // 0..31
    const int tid  = threadIdx.x;
    const int w    = tid >> 6;
    const int lane = tid & 63;
    const int l15  = lane & 15;
    const int q4   = lane >> 4;
    const int qbase = qt * 128 + w * 32;
    const int sw   = l15 & 7;                // K read swizzle
    const int sw_v = q4 ^ (l15 & 3);         // V read swizzle

    // Q fragments resident
    f16x8 qf[2][8];
    #pragma unroll
    for (int s = 0; s < 2; s++) {
        const f16* qp = Qh + ((size_t)(b*4096 + qbase + s*16 + l15)) * 256 + q4*8;
        #pragma unroll
        for (int dc = 0; dc < 8; dc++)
            qf[s][dc] = *(const f16x8*)(qp + dc*32);
    }

    f32x4 Oa[2][16];
    #pragma unroll
    for (int s = 0; s < 2; s++)
        #pragma unroll
        for (int nt = 0; nt < 16; nt++) Oa[s][nt] = (f32x4){0.f,0.f,0.f,0.f};
    float mo[2][4] = {{-3e38f,-3e38f,-3e38f,-3e38f},{-3e38f,-3e38f,-3e38f,-3e38f}};
    float ls[2][4] = {};                     // per-lane partial l

    const f16* kg0 = Kh + ((size_t)(b*4096 + sp*1024)) * 256;  // swizzled image
    const f16* vg0 = Vt + ((size_t)b*256) * 4096 + sp*1024;

    // per-thread DMA slot/source offsets (it-independent)
    int kslot[4], vslot[4], voff[4];
    #pragma unroll
    for (int i = 0; i < 4; i++) {
        int s = tid + i*256;
        kslot[i] = s * 8;
        vslot[i] = s * 8;
        int d = s >> 2;
        int c = (s & 3) ^ (d & 3);
        voff[i] = d * 4096 + c * 8;
    }

    // prologue: DMA K(0) into Ks[0]
    #pragma unroll
    for (int i = 0; i < 4; i++)
        stage16(kg0 + kslot[i], &Ks[0][0] + kslot[i]);

    for (int it = 0; it < 32; it++) {
        const int cur = it & 1;
        __syncthreads();                     // drains K(t), V(t-1) DMAs; guards reuse
        // issue DMAs for the next phase (fly through the whole iteration)
        if (it + 1 < 32) {
            const f16* kg = kg0 + (size_t)(it+1) * 8192;
            f16* kl = &Ks[cur ^ 1][0];
            #pragma unroll
            for (int i = 0; i < 4; i++)
                stage16(kg + kslot[i], kl + kslot[i]);
        }
        {
            const f16* vg = vg0 + it*32;
            f16* vl = &Vs[cur][0];
            #pragma unroll
            for (int i = 0; i < 4; i++)
                stage16(vg + voff[i], vl + vslot[i]);
        }

        // S(t) [+ PV(t-1) interleaved]
        const f16* kr0 = &Ks[cur][(size_t)l15 * 256];
        const f16* kr1 = &Ks[cur][(size_t)(16 + l15) * 256];
        f32x4 sa[2][2] = {{{0.f,0.f,0.f,0.f},{0.f,0.f,0.f,0.f}},
                          {{0.f,0.f,0.f,0.f},{0.f,0.f,0.f,0.f}}};
        if (it > 0) {
            const f16* vprev = &Vs[cur ^ 1][0];
            f16x8 ap0 = *(const f16x8*)&Ps[w][l15][q4*8];
            f16x8 ap1 = *(const f16x8*)&Ps[w][16 + l15][q4*8];
            #pragma unroll
            for (int dc = 0; dc < 8; dc++) {
                int ck = ((dc*4 + q4) ^ sw) << 3;
                f16x8 b0 = *(const f16x8*)(kr0 + ck);
                f16x8 b1 = *(const f16x8*)(kr1 + ck);
                sa[0][0] = __builtin_amdgcn_mfma_f32_16x16x32_f16(qf[0][dc], b0, sa[0][0], 0,0,0);
                sa[0][1] = __builtin_amdgcn_mfma_f32_16x16x32_f16(qf[0][dc], b1, sa[0][1], 0,0,0);
                sa[1][0] = __builtin_amdgcn_mfma_f32_16x16x32_f16(qf[1][dc], b0, sa[1][0], 0,0,0);
                sa[1][1] = __builtin_amdgcn_mfma_f32_16x16x32_f16(qf[1][dc], b1, sa[1][1], 0,0,0);
                #pragma unroll
                for (int u = 0; u < 2; u++) {
                    int nt = dc*2 + u;
                    f16x8 bv = *(const f16x8*)(vprev + (((nt*16 + l15) << 2) + sw_v) * 8);
                    Oa[0][nt] = __builtin_amdgcn_mfma_f32_16x16x32_f16(ap0, bv, Oa[0][nt], 0,0,0);
                    Oa[1][nt] = __builtin_amdgcn_mfma_f32_16x16x32_f16(ap1, bv, Oa[1][nt], 0,0,0);
                }
            }
        } else {
            #pragma unroll
            for (int dc = 0; dc < 8; dc++) {
                int ck = ((dc*4 + q4) ^ sw) << 3;
                f16x8 b0 = *(const f16x8*)(kr0 + ck);
                f16x8 b1 = *(const f16x8*)(kr1 + ck);
                sa[0][0] = __builtin_amdgcn_mfma_f32_16x16x32_f16(qf[0][dc], b0, sa[0][0], 0,0,0);
                sa[0][1] = __builtin_amdgcn_mfma_f32_16x16x32_f16(qf[0][dc], b1, sa[0][1], 0,0,0);
                sa[1][0] = __builtin_amdgcn_mfma_f32_16x16x32_f16(qf[1][dc], b0, sa[1][0], 0,0,0);
                sa[1][1] = __builtin_amdgcn_mfma_f32_16x16x32_f16(qf[1][dc], b1, sa[1][1], 0,0,0);
            }
        }

        // hysteresis softmax(t), P(t) -> Ps
        #pragma unroll
        for (int s = 0; s < 2; s++) {
            float tm[4];
            bool trig = false;
            #pragma unroll
            for (int r = 0; r < 4; r++) {
                tm[r] = fmaxf(sa[s][0][r], sa[s][1][r]);
                trig |= (tm[r] > mo[s][r] + MARGIN);
            }
            if (__any(trig)) {
                #pragma unroll
                for (int off = 1; off < 16; off <<= 1)
                    #pragma unroll
                    for (int r = 0; r < 4; r++)
                        tm[r] = fmaxf(tm[r], __shfl_xor(tm[r], off));
                float al[4];
                #pragma unroll
                for (int r = 0; r < 4; r++) {
                    float mn = fmaxf(mo[s][r], tm[r]);
                    al[r] = __expf(mo[s][r] - mn);
                    mo[s][r] = mn;
                    ls[s][r] *= al[r];
                }
                #pragma unroll
                for (int nt = 0; nt < 16; nt++)
                    #pragma unroll
                    for (int r = 0; r < 4; r++)
                        Oa[s][nt][r] *= al[r];
            }
            #pragma unroll
            for (int r = 0; r < 4; r++) {
                float p0 = __expf(sa[s][0][r] - mo[s][r]);
                float p1 = __expf(sa[s][1][r] - mo[s][r]);
                ls[s][r] += p0 + p1;
                Ps[w][s*16 + q4*4 + r][l15]      = (f16)p0;
                Ps[w][s*16 + q4*4 + r][16 + l15] = (f16)p1;
            }
        }
    }

    // final PV(31): drain V(31) DMA first
    __syncthreads();
    {
        const f16* vlast = &Vs[1][0];        // 31 & 1
        f16x8 ap0 = *(const f16x8*)&Ps[w][l15][q4*8];
        f16x8 ap1 = *(const f16x8*)&Ps[w][16 + l15][q4*8];
        #pragma unroll
        for (int nt = 0; nt < 16; nt++) {
            f16x8 bv = *(const f16x8*)(vlast + (((nt*16 + l15) << 2) + sw_v) * 8);
            Oa[0][nt] = __builtin_amdgcn_mfma_f32_16x16x32_f16(ap0, bv, Oa[0][nt], 0,0,0);
            Oa[1][nt] = __builtin_amdgcn_mfma_f32_16x16x32_f16(ap1, bv, Oa[1][nt], 0,0,0);
        }
    }

    // epilogue: reduce per-lane l, store NORMALIZED partial O (f16) + (m, l)
    #pragma unroll
    for (int s = 0; s < 2; s++) {
        float lsum[4];
        #pragma unroll
        for (int r = 0; r < 4; r++) lsum[r] = ls[s][r];
        #pragma unroll
        for (int off = 1; off < 16; off <<= 1)
            #pragma unroll
            for (int r = 0; r < 4; r++)
                lsum[r] += __shfl_xor(lsum[r], off);
        float inv[4];
        #pragma unroll
        for (int r = 0; r < 4; r++) inv[r] = 1.0f / lsum[r];
        f16* op = Opart + ((size_t)sp*M_ + b*4096 + qbase + s*16) * 256;
        #pragma unroll
        for (int nt = 0; nt < 16; nt++)
            #pragma unroll
            for (int r = 0; r < 4; r++)
                op[(size_t)(q4*4 + r) * 256 + nt*16 + l15] = (f16)(Oa[s][nt][r] * inv[r]);
        if (l15 == 0) {
            #pragma unroll
            for (int r = 0; r < 4; r++) {
                size_t mrow = (size_t)sp*M_ + b*4096 + qbase + s*16 + q4*4 + r;
                Ml[mrow*2]     = mo[s][r];
                Ml[mrow*2 + 1] = lsum[r];
            }
        }
    }
}

// ---------------------------------------------------------------------------
// Kernel 4: merge 4 normalized k-quarter partials + FC (fp16 MFMA) + bias.
// ---------------------------------------------------------------------------
__global__ __launch_bounds__(256) void merge_fc_kernel(
    const f16* __restrict__ Opart, const float* __restrict__ Ml,
    const f16* __restrict__ Wfch, const float* __restrict__ bfc,
    float* __restrict__ out)
{
    const int tid  = threadIdx.x;
    const int w    = tid >> 6;
    const int lane = tid & 63;
    const int l15  = lane & 15;
    const int q4   = lane >> 4;
    const int m0   = blockIdx.x * 64 + w * 16;

    const int rowA = m0 + l15;
    float mv[4], lv[4];
    #pragma unroll
    for (int p = 0; p < 4; p++) {
        mv[p] = Ml[((size_t)p*M_ + rowA)*2];
        lv[p] = Ml[((size_t)p*M_ + rowA)*2 + 1];
    }
    float mm = fmaxf(fmaxf(mv[0], mv[1]), fmaxf(mv[2], mv[3]));
    float cw[4], den = 0.f;
    #pragma unroll
    for (int p = 0; p < 4; p++) { cw[p] = __expf(mv[p] - mm) * lv[p]; den += cw[p]; }
    float inv = 1.0f / den;
    #pragma unroll
    for (int p = 0; p < 4; p++) cw[p] *= inv;

    f16x8 af[8];
    #pragma unroll
    for (int dc = 0; dc < 8; dc++) {
        float v[8] = {};
        #pragma unroll
        for (int p = 0; p < 4; p++) {
            f16x8 o = *(const f16x8*)(Opart + ((size_t)p*M_ + rowA)*256 + q4*8 + dc*32);
            #pragma unroll
            for (int j = 0; j < 8; j++) v[j] += cw[p] * (float)o[j];
        }
        f16x8 h;
        #pragma unroll
        for (int j = 0; j < 8; j++) h[j] = (f16)v[j];
        af[dc] = h;
    }

    f32x4 acc[16];
    #pragma unroll
    for (int nt = 0; nt < 16; nt++) acc[nt] = (f32x4){0.f,0.f,0.f,0.f};
    #pragma unroll
    for (int dc = 0; dc < 8; dc++) {
        #pragma unroll
        for (int nt = 0; nt < 16; nt++) {
            f16x8 bf = *(const f16x8*)(Wfch + (size_t)(nt*16 + l15)*256 + dc*32 + q4*8);
            acc[nt] = __builtin_amdgcn_mfma_f32_16x16x32_f16(af[dc], bf, acc[nt], 0,0,0);
        }
    }
    #pragma unroll
    for (int nt = 0; nt < 16; nt++) {
        float bias = bfc[nt*16 + l15];
        #pragma unroll
        for (int r = 0; r < 4; r++)
            out[(size_t)(m0 + q4*4 + r) * 256 + nt*16 + l15] = acc[nt][r] + bias;
    }
}

// ---------------------------------------------------------------------------
extern "C" void kernel_launch(void* const* d_in, const int* in_sizes, int n_in,
                              void* d_out, int out_size, void* d_ws, size_t ws_size,
                              hipStream_t stream)
{
    const float* x   = (const float*)d_in[0];
    const float* Wq  = (const float*)d_in[1];
    const float* bq  = (const float*)d_in[2];
    const float* Wk  = (const float*)d_in[3];
    const float* bk  = (const float*)d_in[4];
    const float* Wv  = (const float*)d_in[5];
    const float* bv  = (const float*)d_in[6];
    const float* Wfc = (const float*)d_in[7];
    const float* bfc = (const float*)d_in[8];
    float* out = (float*)d_out;

    char* ws = (char*)d_ws;
    f16*   Qh    = (f16*)(ws + QH_OFF);
    f16*   Kh    = (f16*)(ws + KH_OFF);
    f16*   Vt    = (f16*)(ws + VT_OFF);
    f16*   Wfch  = (f16*)(ws + WFCH_OFF);
    f16*   Wqs   = (f16*)(ws + WQS_OFF);
    f16*   Wks   = (f16*)(ws + WKS_OFF);
    f16*   Wvs   = (f16*)(ws + WVS_OFF);
    f16*   Opart = (f16*)(ws + OP_OFF);
    float* Ml    = (float*)(ws + ML_OFF);

    cvt_w<<<dim3(64, 4), 256, 0, stream>>>(Wq, Wk, Wv, Wfc, Wqs, Wks, Wvs, Wfch);
    proj_kernel<<<dim3(256, 3), 256, 0, stream>>>(x, Wqs, Wks, Wvs, bq, bk, bv, Qh, Kh, Vt);
    attn_kernel<<<512, 256, 0, stream>>>(Qh, Kh, Vt, Opart, Ml);
    merge_fc_kernel<<<256, 256, 0, stream>>>(Opart, Ml, Wfch, bfc, out);
}

// Round 7
// 305.986 us; speedup vs baseline: 1.3993x; 1.0416x over previous
//
#include <hip/hip_runtime.h>
#include <stdint.h>

// Problem constants
#define B_ 4
#define N_ 4096
#define D_ 256
#define M_ (B_*N_)   // 16384

typedef _Float16 f16;
typedef _Float16 f16x8 __attribute__((ext_vector_type(8)));
typedef float    f32x4  __attribute__((ext_vector_type(4)));
typedef float    f32x16 __attribute__((ext_vector_type(16)));

#define MFMA16(A,B,C) __builtin_amdgcn_mfma_f32_16x16x32_f16(A,B,C,0,0,0)
#define MFMA32(A,B,C) __builtin_amdgcn_mfma_f32_32x32x16_f16(A,B,C,0,0,0)

// workspace layout (bytes)
#define QH_OFF   0u            // Qh:   16384*256*2 = 8388608
#define KH_OFF   8388608u      // Kh:   8388608 (PRE-SWIZZLED)
#define VT_OFF   16777216u     // Vt:   [4][256][4096] f16 = 8388608
#define WFCH_OFF 25165824u     // Wfch: 131072
#define WQS_OFF  25296896u     // Wqs:  262144 (hi|lo)
#define WKS_OFF  25559040u
#define WVS_OFF  25821184u
#define OP_OFF   26083328u     // Opart: f16 [4][16384][256] = 33554432
#define ML_OFF   59637760u     // Ml: f32 [4][16384][2] = 524288

typedef __attribute__((address_space(3))) uint32_t lds_u32;
typedef __attribute__((address_space(1))) const uint32_t g_u32;

__device__ __forceinline__ void stage16(const f16* g, f16* lbase) {
    __builtin_amdgcn_global_load_lds((g_u32*)g, (lds_u32*)lbase, 16, 0, 0);
}
__device__ __forceinline__ uint32_t pk2(float a, float b) {
    union { f16 h[2]; uint32_t u; } x;
    x.h[0] = (f16)a; x.h[1] = (f16)b;
    return x.u;
}

// ---------------------------------------------------------------------------
// Kernel 1: weight conversion (unchanged).
// ---------------------------------------------------------------------------
__global__ __launch_bounds__(256) void cvt_w(
    const float* __restrict__ Wq, const float* __restrict__ Wk,
    const float* __restrict__ Wv, const float* __restrict__ Wfc,
    f16* __restrict__ Wqs, f16* __restrict__ Wks, f16* __restrict__ Wvs,
    f16* __restrict__ Wfch)
{
    const int z = blockIdx.y;
    const float* W = (z==0) ? Wq : (z==1) ? Wk : (z==2) ? Wv : Wfc;
    int idx = (blockIdx.x * 256 + threadIdx.x) * 4;
    float4 v = *(const float4*)(W + idx);
    union { ushort4 u4; f16 h[4]; } hi, lo;
    float vv[4] = {v.x, v.y, v.z, v.w};
    #pragma unroll
    for (int j = 0; j < 4; j++) {
        hi.h[j] = (f16)vv[j];
        lo.h[j] = (f16)(vv[j] - (float)hi.h[j]);
    }
    if (z == 3) {
        *(ushort4*)(Wfch + idx) = hi.u4;
    } else {
        f16* Ws = (z==0) ? Wqs : (z==1) ? Wks : Wvs;
        int col = idx >> 8, k = idx & 255;
        *(ushort4*)(Ws + col*512 + k)       = hi.u4;
        *(ushort4*)(Ws + col*512 + 256 + k) = lo.u4;
    }
}

// ---------------------------------------------------------------------------
// Kernel 2: QKV projection (f16 MFMA hi/lo). V output transposed via LDS so
// global stores are 128B-coalesced b128.
// ---------------------------------------------------------------------------
__global__ __launch_bounds__(256) void proj_kernel(
    const float* __restrict__ x,
    const f16* __restrict__ Wqs, const f16* __restrict__ Wks,
    const f16* __restrict__ Wvs,
    const float* __restrict__ bq, const float* __restrict__ bk,
    const float* __restrict__ bv,
    f16* __restrict__ Qh, f16* __restrict__ Kh, f16* __restrict__ Vt)
{
    const int z = blockIdx.y;
    const f16*   Ws   = (z==0) ? Wqs : (z==1) ? Wks : Wvs;
    const float* bias = (z==0) ? bq  : (z==1) ? bk  : bv;

    __shared__ uint32_t VTs[256 * 36];   // [e][m-words], stride 36 w

    const int tid  = threadIdx.x;
    const int w    = tid >> 6;
    const int lane = tid & 63;
    const int l15  = lane & 15;
    const int q4   = lane >> 4;
    const int m0   = blockIdx.x * 64 + w * 16;
    const int rowA = m0 + l15;

    f32x4 acc[16];
    #pragma unroll
    for (int nt = 0; nt < 16; nt++) acc[nt] = (f32x4){0.f,0.f,0.f,0.f};

    #pragma unroll
    for (int dc = 0; dc < 8; dc++) {
        float4 a0 = *(const float4*)(x + (size_t)rowA*256 + dc*32 + q4*8);
        float4 a1 = *(const float4*)(x + (size_t)rowA*256 + dc*32 + q4*8 + 4);
        float av[8] = {a0.x,a0.y,a0.z,a0.w,a1.x,a1.y,a1.z,a1.w};
        f16x8 ah, alo;
        #pragma unroll
        for (int j = 0; j < 8; j++) {
            ah[j]  = (f16)av[j];
            alo[j] = (f16)(av[j] - (float)ah[j]);
        }
        #pragma unroll
        for (int nt = 0; nt < 16; nt++) {
            const f16* bp = Ws + (size_t)(nt*16 + l15)*512 + dc*32 + q4*8;
            f16x8 bh = *(const f16x8*)bp;
            f16x8 bl = *(const f16x8*)(bp + 256);
            acc[nt] = MFMA16(ah,  bl, acc[nt]);
            acc[nt] = MFMA16(alo, bh, acc[nt]);
            acc[nt] = MFMA16(ah,  bh, acc[nt]);
        }
    }

    if (z == 0) {
        #pragma unroll
        for (int nt = 0; nt < 16; nt++) {
            float bb = bias[nt*16 + l15];
            #pragma unroll
            for (int r = 0; r < 4; r++)
                Qh[(size_t)(m0 + q4*4 + r)*256 + nt*16 + l15] = (f16)(acc[nt][r] + bb);
        }
    } else if (z == 1) {
        // swizzled Kh image for attn's DMA staging
        const int cbase = (l15 >> 3);
        const int j     = l15 & 7;
        #pragma unroll
        for (int nt = 0; nt < 16; nt++) {
            float bb = bias[nt*16 + l15];
            int c = nt*2 + cbase;
            #pragma unroll
            for (int r = 0; r < 4; r++) {
                int m = m0 + q4*4 + r;
                Kh[(size_t)m*256 + (size_t)((c ^ (m & 7)) << 3) + j] = (f16)(acc[nt][r] + bb);
            }
        }
    } else {
        // V: transpose through LDS, coalesced b128 stores to Vt[b][e][n]
        const int bb_ = m0 >> 12;
        const int n0  = (blockIdx.x * 64) & 4095;
        const int mloc = w*16 + q4*4;
        const int mc   = mloc >> 3;
        #pragma unroll
        for (int nt = 0; nt < 16; nt++) {
            int e = nt*16 + l15;
            float bv_ = bias[e];
            uint32_t w0 = pk2(acc[nt][0]+bv_, acc[nt][1]+bv_);
            uint32_t w1 = pk2(acc[nt][2]+bv_, acc[nt][3]+bv_);
            int base = e*36 + ((mc ^ (e & 7)) << 2) + ((q4*2) & 3);
            VTs[base]     = w0;
            VTs[base + 1] = w1;
        }
        __syncthreads();
        #pragma unroll
        for (int i = 0; i < 8; i++) {
            int e  = w*64 + i*8 + (lane >> 3);
            int nc = lane & 7;
            const f16* src = (const f16*)&VTs[e*36 + ((nc ^ (e & 7)) << 2)];
            f16x8 v = *(const f16x8*)src;
            *(f16x8*)(Vt + ((size_t)bb_*256 + e)*4096 + n0 + nc*8) = v;
        }
    }
}

// ---------------------------------------------------------------------------
// Kernel 3: flash attention, TRANSPOSED compute with 32x32x16 MFMA.
// S^T = K·Q^T -> per-lane softmax (q = lane column, no shuffles common path).
// P^T B-frags built in registers (pack + shfl_xor(32)) — no P LDS round-trip.
// O^T = V^T·P^T in C-layout; un-transposed once in the epilogue via LDS.
// Single barrier/iter; K,V staged by global_load_lds double buffers.
// R7 FIX: epilogue row base used qbase + w*32 (double-counting w*32, already
// in qbase) -> waves 1-3 stored to wrong rows. Now qbase only.
// ---------------------------------------------------------------------------
#define MARGIN 10.0f
__global__ __launch_bounds__(256, 2) void attn_kernel(
    const f16* __restrict__ Qh, const f16* __restrict__ Kh,
    const f16* __restrict__ Vt,
    f16* __restrict__ Opart, float* __restrict__ Ml)
{
    __shared__ __align__(16) f16 SMEM[32768];     // Ks[2][8192] | Vs[2][8192]
    f16* Ks = SMEM;
    f16* Vs = SMEM + 16384;

    const int combo = blockIdx.x & 15;
    const int b   = combo >> 2;
    const int sp  = combo & 3;
    const int qt  = blockIdx.x >> 4;              // 0..31
    const int tid  = threadIdx.x;
    const int w    = tid >> 6;
    const int lane = tid & 63;
    const int l31  = lane & 31;                   // q column
    const int half = lane >> 5;
    const int qbase = qt * 128 + w * 32;          // wave's q-row base (incl. w)
    const int vx   = (l31 >> 2) & 3;              // V image swizzle key

    // Q as B-frags (16 steps of d): lane holds Q[q][8d]
    f16x8 qf[16];
    {
        const f16* qp = Qh + ((size_t)(b*4096 + qbase + l31))*256 + half*8;
        #pragma unroll
        for (int st = 0; st < 16; st++) qf[st] = *(const f16x8*)(qp + st*16);
    }

    f32x16 Oa[8];                                 // O^T d-tiles (C-layout)
    #pragma unroll
    for (int t = 0; t < 8; t++)
        #pragma unroll
        for (int r = 0; r < 16; r++) Oa[t][r] = 0.f;
    float mo = -3e38f, ls = 0.f;                  // per-lane (q = l31)

    const f16* kg0 = Kh + ((size_t)(b*4096 + sp*1024)) * 256;   // swizzled
    const f16* vg0 = Vt + ((size_t)b*256) * 4096 + sp*1024;

    int kslot[4], voff[4];
    #pragma unroll
    for (int i = 0; i < 4; i++) {
        int s = tid + i*256;
        kslot[i] = s * 8;
        int d = s >> 2;
        int kc = (s & 3) ^ ((s >> 4) & 3);        // image: pos = kc ^ ((d>>2)&3)
        voff[i] = d * 4096 + kc * 8;
    }

    // prologue: DMA K(0)
    #pragma unroll
    for (int i = 0; i < 4; i++) stage16(kg0 + kslot[i], Ks + kslot[i]);

    f16x8 bp0, bp1;                               // carried P^T B-frags

    for (int it = 0; it < 32; it++) {
        const int cur = it & 1;
        __syncthreads();                          // drains K(t), V(t-1) DMAs
        if (it + 1 < 32) {
            const f16* kg = kg0 + (size_t)(it+1) * 8192;
            f16* kl = Ks + (cur ^ 1) * 8192;
            #pragma unroll
            for (int i = 0; i < 4; i++) stage16(kg + kslot[i], kl + kslot[i]);
        }
        {
            const f16* vg = vg0 + it*32;
            f16* vl = Vs + cur * 8192;
            #pragma unroll
            for (int i = 0; i < 4; i++) stage16(vg + voff[i], vl + kslot[i]);
        }

        // S^T(t) interleaved with PV(t-1): 32 MFMAs
        const f16* krp = Ks + cur*8192 + l31*256;
        const f16* vpp = Vs + (cur^1)*8192 + l31*32;
        f32x16 sa;
        #pragma unroll
        for (int r = 0; r < 16; r++) sa[r] = 0.f;
        if (it > 0) {
            #pragma unroll
            for (int st = 0; st < 16; st++) {
                f16x8 ka = *(const f16x8*)(krp + (((st*2 + half) ^ (lane & 7)) << 3));
                sa = MFMA32(ka, qf[st], sa);
                int t = st >> 1, kh = st & 1;
                f16x8 va = *(const f16x8*)(vpp + t*1024 + (((half + kh*2) ^ vx) << 3));
                Oa[t] = MFMA32(va, kh ? bp1 : bp0, Oa[t]);
            }
        } else {
            #pragma unroll
            for (int st = 0; st < 16; st++) {
                f16x8 ka = *(const f16x8*)(krp + (((st*2 + half) ^ (lane & 7)) << 3));
                sa = MFMA32(ka, qf[st], sa);
            }
        }

        // per-lane hysteresis softmax (q = lane col)
        float tm = sa[0];
        #pragma unroll
        for (int r = 1; r < 16; r++) tm = fmaxf(tm, sa[r]);
        if (__any(tm > mo + MARGIN)) {
            float tmq = fmaxf(tm, __shfl_xor(tm, 32));
            float mn = fmaxf(mo, tmq);
            float al = __expf(mo - mn);
            mo = mn; ls *= al;
            #pragma unroll
            for (int t = 0; t < 8; t++)
                #pragma unroll
                for (int r = 0; r < 16; r++) Oa[t][r] *= al;
        }
        float p[16];
        #pragma unroll
        for (int r = 0; r < 16; r++) { p[r] = __expf(sa[r] - mo); ls += p[r]; }

        // build P^T B-frags: keys 16kh + [0..7](h=0) / [8..15](h=1)
        #pragma unroll
        for (int kh = 0; kh < 2; kh++) {
            uint32_t lo0 = pk2(p[8*kh+0], p[8*kh+1]);
            uint32_t lo1 = pk2(p[8*kh+2], p[8*kh+3]);
            uint32_t hi0 = pk2(p[8*kh+4], p[8*kh+5]);
            uint32_t hi1 = pk2(p[8*kh+6], p[8*kh+7]);
            uint32_t s0 = half ? lo0 : hi0;
            uint32_t s1 = half ? lo1 : hi1;
            uint32_t r0 = __shfl_xor(s0, 32);
            uint32_t r1 = __shfl_xor(s1, 32);
            uint32_t k0 = half ? hi0 : lo0;
            uint32_t k1 = half ? hi1 : lo1;
            union { uint32_t u[4]; f16x8 v; } bb;
            bb.u[0] = half ? r0 : k0;
            bb.u[1] = half ? r1 : k1;
            bb.u[2] = half ? k0 : r0;
            bb.u[3] = half ? k1 : r1;
            if (kh == 0) bp0 = bb.v; else bp1 = bb.v;
        }
    }

    // final PV(31): drain V(31) DMA, then consume
    __syncthreads();
    {
        const f16* vpp = Vs + 8192 + l31*32;      // V(31) in Vs[1]
        #pragma unroll
        for (int t = 0; t < 8; t++) {
            #pragma unroll
            for (int kh = 0; kh < 2; kh++) {
                f16x8 va = *(const f16x8*)(vpp + t*1024 + (((half + kh*2) ^ vx) << 3));
                Oa[t] = MFMA32(va, kh ? bp1 : bp0, Oa[t]);
            }
        }
    }
    __syncthreads();                              // all waves done with SMEM tiles

    // epilogue: l across half-pair, normalize, un-transpose via per-wave LDS
    float l = ls + __shfl_xor(ls, 32);
    float inv = 1.0f / l;
    f16* tb = SMEM + w * 8192;                    // 16KB per wave
    #pragma unroll
    for (int t = 0; t < 8; t++) {
        #pragma unroll
        for (int rp = 0; rp < 8; rp++) {
            int r0 = rp * 2;
            int d  = (r0 & 3) + 8*(r0 >> 2) + 4*half + t*32;
            int c  = d >> 3, j = d & 7;
            uint32_t wv = pk2(Oa[t][r0]*inv, Oa[t][r0+1]*inv);
            *(uint32_t*)(tb + l31*256 + ((c ^ (l31 & 7)) << 3) + (j & 6)) = wv;
        }
    }
    // coalesced read-back + global store (per-wave region, rows = qbase+q)
    f16* opb = Opart + ((size_t)sp*M_ + b*4096 + qbase) * 256;   // R7 FIX
    #pragma unroll
    for (int i = 0; i < 16; i++) {
        int q = (i & 3)*8 + (lane >> 3);
        int c = (i >> 2)*8 + (lane & 7);
        f16x8 v = *(const f16x8*)(tb + q*256 + ((c ^ (q & 7)) << 3));
        *(f16x8*)(opb + (size_t)q*256 + c*8) = v;
    }
    if (half == 0) {
        size_t mrow = (size_t)sp*M_ + b*4096 + qbase + l31;      // R7 FIX
        Ml[mrow*2]     = mo;
        Ml[mrow*2 + 1] = l;
    }
}

// ---------------------------------------------------------------------------
// Kernel 4: merge 4 normalized k-quarter partials + FC (fp16 MFMA) + bias.
// ---------------------------------------------------------------------------
__global__ __launch_bounds__(256) void merge_fc_kernel(
    const f16* __restrict__ Opart, const float* __restrict__ Ml,
    const f16* __restrict__ Wfch, const float* __restrict__ bfc,
    float* __restrict__ out)
{
    const int tid  = threadIdx.x;
    const int w    = tid >> 6;
    const int lane = tid & 63;
    const int l15  = lane & 15;
    const int q4   = lane >> 4;
    const int m0   = blockIdx.x * 64 + w * 16;

    const int rowA = m0 + l15;
    float mv[4], lv[4];
    #pragma unroll
    for (int p = 0; p < 4; p++) {
        mv[p] = Ml[((size_t)p*M_ + rowA)*2];
        lv[p] = Ml[((size_t)p*M_ + rowA)*2 + 1];
    }
    float mm = fmaxf(fmaxf(mv[0], mv[1]), fmaxf(mv[2], mv[3]));
    float cw[4], den = 0.f;
    #pragma unroll
    for (int p = 0; p < 4; p++) { cw[p] = __expf(mv[p] - mm) * lv[p]; den += cw[p]; }
    float inv = 1.0f / den;
    #pragma unroll
    for (int p = 0; p < 4; p++) cw[p] *= inv;

    f16x8 af[8];
    #pragma unroll
    for (int dc = 0; dc < 8; dc++) {
        float v[8] = {};
        #pragma unroll
        for (int p = 0; p < 4; p++) {
            f16x8 o = *(const f16x8*)(Opart + ((size_t)p*M_ + rowA)*256 + q4*8 + dc*32);
            #pragma unroll
            for (int j = 0; j < 8; j++) v[j] += cw[p] * (float)o[j];
        }
        f16x8 h;
        #pragma unroll
        for (int j = 0; j < 8; j++) h[j] = (f16)v[j];
        af[dc] = h;
    }

    f32x4 acc[16];
    #pragma unroll
    for (int nt = 0; nt < 16; nt++) acc[nt] = (f32x4){0.f,0.f,0.f,0.f};
    #pragma unroll
    for (int dc = 0; dc < 8; dc++) {
        #pragma unroll
        for (int nt = 0; nt < 16; nt++) {
            f16x8 bf = *(const f16x8*)(Wfch + (size_t)(nt*16 + l15)*256 + dc*32 + q4*8);
            acc[nt] = MFMA16(af[dc], bf, acc[nt]);
        }
    }
    #pragma unroll
    for (int nt = 0; nt < 16; nt++) {
        float bias = bfc[nt*16 + l15];
        #pragma unroll
        for (int r = 0; r < 4; r++)
            out[(size_t)(m0 + q4*4 + r) * 256 + nt*16 + l15] = acc[nt][r] + bias;
    }
}

// ---------------------------------------------------------------------------
extern "C" void kernel_launch(void* const* d_in, const int* in_sizes, int n_in,
                              void* d_out, int out_size, void* d_ws, size_t ws_size,
                              hipStream_t stream)
{
    const float* x   = (const float*)d_in[0];
    const float* Wq  = (const float*)d_in[1];
    const float* bq  = (const float*)d_in[2];
    const float* Wk  = (const float*)d_in[3];
    const float* bk  = (const float*)d_in[4];
    const float* Wv  = (const float*)d_in[5];
    const float* bv  = (const float*)d_in[6];
    const float* Wfc = (const float*)d_in[7];
    const float* bfc = (const float*)d_in[8];
    float* out = (float*)d_out;

    char* ws = (char*)d_ws;
    f16*   Qh    = (f16*)(ws + QH_OFF);
    f16*   Kh    = (f16*)(ws + KH_OFF);
    f16*   Vt    = (f16*)(ws + VT_OFF);
    f16*   Wfch  = (f16*)(ws + WFCH_OFF);
    f16*   Wqs   = (f16*)(ws + WQS_OFF);
    f16*   Wks   = (f16*)(ws + WKS_OFF);
    f16*   Wvs   = (f16*)(ws + WVS_OFF);
    f16*   Opart = (f16*)(ws + OP_OFF);
    float* Ml    = (float*)(ws + ML_OFF);

    cvt_w<<<dim3(64, 4), 256, 0, stream>>>(Wq, Wk, Wv, Wfc, Wqs, Wks, Wvs, Wfch);
    proj_kernel<<<dim3(256, 3), 256, 0, stream>>>(x, Wqs, Wks, Wvs, bq, bk, bv, Qh, Kh, Vt);
    attn_kernel<<<512, 256, 0, stream>>>(Qh, Kh, Vt, Opart, Ml);
    merge_fc_kernel<<<256, 256, 0, stream>>>(Opart, Ml, Wfch, bfc, out);
}

// Round 8
// 218.375 us; speedup vs baseline: 1.9607x; 1.4012x over previous
//
#include <hip/hip_runtime.h>
#include <stdint.h>

// Problem constants
#define B_ 4
#define N_ 4096
#define D_ 256
#define M_ (B_*N_)   // 16384

typedef _Float16 f16;
typedef _Float16 f16x8 __attribute__((ext_vector_type(8)));
typedef float    f32x4  __attribute__((ext_vector_type(4)));
typedef float    f32x16 __attribute__((ext_vector_type(16)));

#define MFMA16(A,B,C) __builtin_amdgcn_mfma_f32_16x16x32_f16(A,B,C,0,0,0)
#define MFMA32(A,B,C) __builtin_amdgcn_mfma_f32_32x32x16_f16(A,B,C,0,0,0)

// workspace layout (bytes)
#define QH_OFF   0u            // Qh:   16384*256*2 = 8388608
#define KH_OFF   8388608u      // Kh:   8388608 (PRE-SWIZZLED)
#define VT_OFF   16777216u     // Vt:   [4][256][4096] f16 = 8388608
#define WFCH_OFF 25165824u     // Wfch: 131072
#define WQS_OFF  25296896u     // Wqs:  262144 (DMA image, hi|lo per dc-slab)
#define WKS_OFF  25559040u
#define WVS_OFF  25821184u
#define OP_OFF   26083328u     // Opart: f16 [4][16384][256] = 33554432
#define ML_OFF   59637760u     // Ml: f32 [4][16384][2] = 524288

typedef __attribute__((address_space(3))) uint32_t lds_u32;
typedef __attribute__((address_space(1))) const uint32_t g_u32;

__device__ __forceinline__ void stage16(const f16* g, f16* lbase) {
    __builtin_amdgcn_global_load_lds((g_u32*)g, (lds_u32*)lbase, 16, 0, 0);
}
__device__ __forceinline__ uint32_t pk2(float a, float b) {
    union { f16 h[2]; uint32_t u; } x;
    x.h[0] = (f16)a; x.h[1] = (f16)b;
    return x.u;
}

// ---------------------------------------------------------------------------
// Kernel 1: weight conversion.
// z<3: DMA-ready image for proj staging:
//   element (col e, k) -> Ws[(k>>5)*16384 + t*8192 + e*32 + p*8 + (k&7)]
//   where t=0 hi / 1 lo, chunk c8=(k>>3)&3 stored at pos p = c8 ^ ((e>>2)&3).
//   One dc-slab (32KB) is contiguous -> linear global_load_lds staging; the
//   pos-swizzle makes proj's ds_read_b128 bank-uniform.
// z==3: Wfc -> plain f16.
// ---------------------------------------------------------------------------
__global__ __launch_bounds__(256) void cvt_w(
    const float* __restrict__ Wq, const float* __restrict__ Wk,
    const float* __restrict__ Wv, const float* __restrict__ Wfc,
    f16* __restrict__ Wqs, f16* __restrict__ Wks, f16* __restrict__ Wvs,
    f16* __restrict__ Wfch)
{
    const int z = blockIdx.y;
    const float* W = (z==0) ? Wq : (z==1) ? Wk : (z==2) ? Wv : Wfc;
    int idx = (blockIdx.x * 256 + threadIdx.x) * 4;
    float4 v = *(const float4*)(W + idx);
    union { ushort4 u4; f16 h[4]; } hi, lo;
    float vv[4] = {v.x, v.y, v.z, v.w};
    #pragma unroll
    for (int j = 0; j < 4; j++) {
        hi.h[j] = (f16)vv[j];
        lo.h[j] = (f16)(vv[j] - (float)hi.h[j]);
    }
    if (z == 3) {
        *(ushort4*)(Wfch + idx) = hi.u4;
    } else {
        f16* Ws = (z==0) ? Wqs : (z==1) ? Wks : Wvs;
        int col = idx >> 8, k = idx & 255;
        int dc = k >> 5, c8 = (k >> 3) & 3, j = k & 7;
        int p  = c8 ^ ((col >> 2) & 3);
        int base = dc*16384 + col*32 + p*8 + j;
        *(ushort4*)(Ws + base)        = hi.u4;
        *(ushort4*)(Ws + base + 8192) = lo.u4;
    }
}

// ---------------------------------------------------------------------------
// Kernel 2: QKV projection (f16 MFMA hi/lo). R8: B-fragments staged via
// global_load_lds into double-buffered LDS (32KB/slab), issued one dc-step
// ahead — removes the serialized L2 round-trips that made R3-R7 proj
// latency-bound (123us, MfmaUtil 5.6%). x chunk prefetched per step.
// V output transposed via LDS (buffer unioned with the staging buffers).
// ---------------------------------------------------------------------------
__global__ __launch_bounds__(256, 2) void proj_kernel(
    const float* __restrict__ x,
    const f16* __restrict__ Wqs, const f16* __restrict__ Wks,
    const f16* __restrict__ Wvs,
    const float* __restrict__ bq, const float* __restrict__ bk,
    const float* __restrict__ bv,
    f16* __restrict__ Qh, f16* __restrict__ Kh, f16* __restrict__ Vt)
{
    const int z = blockIdx.y;
    const f16*   Ws   = (z==0) ? Wqs : (z==1) ? Wks : Wvs;
    const float* bias = (z==0) ? bq  : (z==1) ? bk  : bv;

    __shared__ __align__(16) f16 Bs[2][16384];   // 64KB dbuf; VTs union below

    const int tid  = threadIdx.x;
    const int w    = tid >> 6;
    const int lane = tid & 63;
    const int l15  = lane & 15;
    const int q4   = lane >> 4;
    const int m0   = blockIdx.x * 64 + w * 16;
    const int rowA = m0 + l15;
    const int sw   = (l15 >> 2) & 3;             // B read swizzle key

    int s8[8];
    #pragma unroll
    for (int i = 0; i < 8; i++) s8[i] = (tid + i*256) * 8;

    f32x4 acc[16];
    #pragma unroll
    for (int nt = 0; nt < 16; nt++) acc[nt] = (f32x4){0.f,0.f,0.f,0.f};

    // prologue: DMA slab 0, load x chunk 0
    #pragma unroll
    for (int i = 0; i < 8; i++) stage16(Ws + s8[i], &Bs[0][0] + s8[i]);
    const float* xp = x + (size_t)rowA * 256;
    float4 a0 = *(const float4*)(xp + q4*8);
    float4 a1 = *(const float4*)(xp + q4*8 + 4);

    for (int dc = 0; dc < 8; dc++) {
        const int cur = dc & 1;
        __syncthreads();                         // drains DMA(dc); prev reads done
        if (dc < 7) {                            // DMA slab dc+1 (flies over compute)
            const f16* src = Ws + (size_t)(dc+1)*16384;
            f16* dst = &Bs[cur ^ 1][0];
            #pragma unroll
            for (int i = 0; i < 8; i++) stage16(src + s8[i], dst + s8[i]);
        }
        float av[8] = {a0.x,a0.y,a0.z,a0.w,a1.x,a1.y,a1.z,a1.w};
        f16x8 ah, alo;
        #pragma unroll
        for (int j = 0; j < 8; j++) {
            ah[j]  = (f16)av[j];
            alo[j] = (f16)(av[j] - (float)ah[j]);
        }
        if (dc < 7) {                            // prefetch next x chunk
            a0 = *(const float4*)(xp + (dc+1)*32 + q4*8);
            a1 = *(const float4*)(xp + (dc+1)*32 + q4*8 + 4);
        }
        const f16* Bc = &Bs[cur][0];
        #pragma unroll
        for (int nt = 0; nt < 16; nt++) {
            const f16* bp = Bc + (nt*16 + l15)*32 + ((q4 ^ sw) << 3);
            f16x8 bh = *(const f16x8*)bp;
            f16x8 bl = *(const f16x8*)(bp + 8192);
            acc[nt] = MFMA16(ah,  bl, acc[nt]);
            acc[nt] = MFMA16(alo, bh, acc[nt]);
            acc[nt] = MFMA16(ah,  bh, acc[nt]);
        }
    }

    if (z == 0) {
        #pragma unroll
        for (int nt = 0; nt < 16; nt++) {
            float bb = bias[nt*16 + l15];
            #pragma unroll
            for (int r = 0; r < 4; r++)
                Qh[(size_t)(m0 + q4*4 + r)*256 + nt*16 + l15] = (f16)(acc[nt][r] + bb);
        }
    } else if (z == 1) {
        // swizzled Kh image for attn's DMA staging
        const int cbase = (l15 >> 3);
        const int j     = l15 & 7;
        #pragma unroll
        for (int nt = 0; nt < 16; nt++) {
            float bb = bias[nt*16 + l15];
            int c = nt*2 + cbase;
            #pragma unroll
            for (int r = 0; r < 4; r++) {
                int m = m0 + q4*4 + r;
                Kh[(size_t)m*256 + (size_t)((c ^ (m & 7)) << 3) + j] = (f16)(acc[nt][r] + bb);
            }
        }
    } else {
        // V: transpose through LDS (unions with Bs), coalesced b128 stores
        uint32_t* VTs = (uint32_t*)&Bs[0][0];    // needs 36864B of the 64KB
        const int bb_ = m0 >> 12;
        const int n0  = (blockIdx.x * 64) & 4095;
        const int mloc = w*16 + q4*4;
        const int mc   = mloc >> 3;
        __syncthreads();                         // all waves done reading Bs
        #pragma unroll
        for (int nt = 0; nt < 16; nt++) {
            int e = nt*16 + l15;
            float bv_ = bias[e];
            uint32_t w0 = pk2(acc[nt][0]+bv_, acc[nt][1]+bv_);
            uint32_t w1 = pk2(acc[nt][2]+bv_, acc[nt][3]+bv_);
            int base = e*36 + ((mc ^ (e & 7)) << 2) + ((q4*2) & 3);
            VTs[base]     = w0;
            VTs[base + 1] = w1;
        }
        __syncthreads();
        #pragma unroll
        for (int i = 0; i < 8; i++) {
            int e  = w*64 + i*8 + (lane >> 3);
            int nc = lane & 7;
            const f16* src = (const f16*)&VTs[e*36 + ((nc ^ (e & 7)) << 2)];
            f16x8 v = *(const f16x8*)src;
            *(f16x8*)(Vt + ((size_t)bb_*256 + e)*4096 + n0 + nc*8) = v;
        }
    }
}

// ---------------------------------------------------------------------------
// Kernel 3: flash attention, TRANSPOSED compute with 32x32x16 MFMA.
// (unchanged from R7 — verified)
// ---------------------------------------------------------------------------
#define MARGIN 10.0f
__global__ __launch_bounds__(256, 2) void attn_kernel(
    const f16* __restrict__ Qh, const f16* __restrict__ Kh,
    const f16* __restrict__ Vt,
    f16* __restrict__ Opart, float* __restrict__ Ml)
{
    __shared__ __align__(16) f16 SMEM[32768];     // Ks[2][8192] | Vs[2][8192]
    f16* Ks = SMEM;
    f16* Vs = SMEM + 16384;

    const int combo = blockIdx.x & 15;
    const int b   = combo >> 2;
    const int sp  = combo & 3;
    const int qt  = blockIdx.x >> 4;              // 0..31
    const int tid  = threadIdx.x;
    const int w    = tid >> 6;
    const int lane = tid & 63;
    const int l31  = lane & 31;                   // q column
    const int half = lane >> 5;
    const int qbase = qt * 128 + w * 32;          // wave's q-row base (incl. w)
    const int vx   = (l31 >> 2) & 3;              // V image swizzle key

    // Q as B-frags (16 steps of d): lane holds Q[q][8d]
    f16x8 qf[16];
    {
        const f16* qp = Qh + ((size_t)(b*4096 + qbase + l31))*256 + half*8;
        #pragma unroll
        for (int st = 0; st < 16; st++) qf[st] = *(const f16x8*)(qp + st*16);
    }

    f32x16 Oa[8];                                 // O^T d-tiles (C-layout)
    #pragma unroll
    for (int t = 0; t < 8; t++)
        #pragma unroll
        for (int r = 0; r < 16; r++) Oa[t][r] = 0.f;
    float mo = -3e38f, ls = 0.f;                  // per-lane (q = l31)

    const f16* kg0 = Kh + ((size_t)(b*4096 + sp*1024)) * 256;   // swizzled
    const f16* vg0 = Vt + ((size_t)b*256) * 4096 + sp*1024;

    int kslot[4], voff[4];
    #pragma unroll
    for (int i = 0; i < 4; i++) {
        int s = tid + i*256;
        kslot[i] = s * 8;
        int d = s >> 2;
        int kc = (s & 3) ^ ((s >> 4) & 3);        // image: pos = kc ^ ((d>>2)&3)
        voff[i] = d * 4096 + kc * 8;
    }

    // prologue: DMA K(0)
    #pragma unroll
    for (int i = 0; i < 4; i++) stage16(kg0 + kslot[i], Ks + kslot[i]);

    f16x8 bp0, bp1;                               // carried P^T B-frags

    for (int it = 0; it < 32; it++) {
        const int cur = it & 1;
        __syncthreads();                          // drains K(t), V(t-1) DMAs
        if (it + 1 < 32) {
            const f16* kg = kg0 + (size_t)(it+1) * 8192;
            f16* kl = Ks + (cur ^ 1) * 8192;
            #pragma unroll
            for (int i = 0; i < 4; i++) stage16(kg + kslot[i], kl + kslot[i]);
        }
        {
            const f16* vg = vg0 + it*32;
            f16* vl = Vs + cur * 8192;
            #pragma unroll
            for (int i = 0; i < 4; i++) stage16(vg + voff[i], vl + kslot[i]);
        }

        // S^T(t) interleaved with PV(t-1): 32 MFMAs
        const f16* krp = Ks + cur*8192 + l31*256;
        const f16* vpp = Vs + (cur^1)*8192 + l31*32;
        f32x16 sa;
        #pragma unroll
        for (int r = 0; r < 16; r++) sa[r] = 0.f;
        if (it > 0) {
            #pragma unroll
            for (int st = 0; st < 16; st++) {
                f16x8 ka = *(const f16x8*)(krp + (((st*2 + half) ^ (lane & 7)) << 3));
                sa = MFMA32(ka, qf[st], sa);
                int t = st >> 1, kh = st & 1;
                f16x8 va = *(const f16x8*)(vpp + t*1024 + (((half + kh*2) ^ vx) << 3));
                Oa[t] = MFMA32(va, kh ? bp1 : bp0, Oa[t]);
            }
        } else {
            #pragma unroll
            for (int st = 0; st < 16; st++) {
                f16x8 ka = *(const f16x8*)(krp + (((st*2 + half) ^ (lane & 7)) << 3));
                sa = MFMA32(ka, qf[st], sa);
            }
        }

        // per-lane hysteresis softmax (q = lane col)
        float tm = sa[0];
        #pragma unroll
        for (int r = 1; r < 16; r++) tm = fmaxf(tm, sa[r]);
        if (__any(tm > mo + MARGIN)) {
            float tmq = fmaxf(tm, __shfl_xor(tm, 32));
            float mn = fmaxf(mo, tmq);
            float al = __expf(mo - mn);
            mo = mn; ls *= al;
            #pragma unroll
            for (int t = 0; t < 8; t++)
                #pragma unroll
                for (int r = 0; r < 16; r++) Oa[t][r] *= al;
        }
        float p[16];
        #pragma unroll
        for (int r = 0; r < 16; r++) { p[r] = __expf(sa[r] - mo); ls += p[r]; }

        // build P^T B-frags: keys 16kh + [0..7](h=0) / [8..15](h=1)
        #pragma unroll
        for (int kh = 0; kh < 2; kh++) {
            uint32_t lo0 = pk2(p[8*kh+0], p[8*kh+1]);
            uint32_t lo1 = pk2(p[8*kh+2], p[8*kh+3]);
            uint32_t hi0 = pk2(p[8*kh+4], p[8*kh+5]);
            uint32_t hi1 = pk2(p[8*kh+6], p[8*kh+7]);
            uint32_t s0 = half ? lo0 : hi0;
            uint32_t s1 = half ? lo1 : hi1;
            uint32_t r0 = __shfl_xor(s0, 32);
            uint32_t r1 = __shfl_xor(s1, 32);
            uint32_t k0 = half ? hi0 : lo0;
            uint32_t k1 = half ? hi1 : lo1;
            union { uint32_t u[4]; f16x8 v; } bb;
            bb.u[0] = half ? r0 : k0;
            bb.u[1] = half ? r1 : k1;
            bb.u[2] = half ? k0 : r0;
            bb.u[3] = half ? k1 : r1;
            if (kh == 0) bp0 = bb.v; else bp1 = bb.v;
        }
    }

    // final PV(31): drain V(31) DMA, then consume
    __syncthreads();
    {
        const f16* vpp = Vs + 8192 + l31*32;      // V(31) in Vs[1]
        #pragma unroll
        for (int t = 0; t < 8; t++) {
            #pragma unroll
            for (int kh = 0; kh < 2; kh++) {
                f16x8 va = *(const f16x8*)(vpp + t*1024 + (((half + kh*2) ^ vx) << 3));
                Oa[t] = MFMA32(va, kh ? bp1 : bp0, Oa[t]);
            }
        }
    }
    __syncthreads();                              // all waves done with SMEM tiles

    // epilogue: l across half-pair, normalize, un-transpose via per-wave LDS
    float l = ls + __shfl_xor(ls, 32);
    float inv = 1.0f / l;
    f16* tb = SMEM + w * 8192;                    // 16KB per wave
    #pragma unroll
    for (int t = 0; t < 8; t++) {
        #pragma unroll
        for (int rp = 0; rp < 8; rp++) {
            int r0 = rp * 2;
            int d  = (r0 & 3) + 8*(r0 >> 2) + 4*half + t*32;
            int c  = d >> 3, j = d & 7;
            uint32_t wv = pk2(Oa[t][r0]*inv, Oa[t][r0+1]*inv);
            *(uint32_t*)(tb + l31*256 + ((c ^ (l31 & 7)) << 3) + (j & 6)) = wv;
        }
    }
    // coalesced read-back + global store (per-wave region, rows = qbase+q)
    f16* opb = Opart + ((size_t)sp*M_ + b*4096 + qbase) * 256;
    #pragma unroll
    for (int i = 0; i < 16; i++) {
        int q = (i & 3)*8 + (lane >> 3);
        int c = (i >> 2)*8 + (lane & 7);
        f16x8 v = *(const f16x8*)(tb + q*256 + ((c ^ (q & 7)) << 3));
        *(f16x8*)(opb + (size_t)q*256 + c*8) = v;
    }
    if (half == 0) {
        size_t mrow = (size_t)sp*M_ + b*4096 + qbase + l31;
        Ml[mrow*2]     = mo;
        Ml[mrow*2 + 1] = l;
    }
}

// ---------------------------------------------------------------------------
// Kernel 4: merge 4 normalized k-quarter partials + FC (fp16 MFMA) + bias.
// ---------------------------------------------------------------------------
__global__ __launch_bounds__(256) void merge_fc_kernel(
    const f16* __restrict__ Opart, const float* __restrict__ Ml,
    const f16* __restrict__ Wfch, const float* __restrict__ bfc,
    float* __restrict__ out)
{
    const int tid  = threadIdx.x;
    const int w    = tid >> 6;
    const int lane = tid & 63;
    const int l15  = lane & 15;
    const int q4   = lane >> 4;
    const int m0   = blockIdx.x * 64 + w * 16;

    const int rowA = m0 + l15;
    float mv[4], lv[4];
    #pragma unroll
    for (int p = 0; p < 4; p++) {
        mv[p] = Ml[((size_t)p*M_ + rowA)*2];
        lv[p] = Ml[((size_t)p*M_ + rowA)*2 + 1];
    }
    float mm = fmaxf(fmaxf(mv[0], mv[1]), fmaxf(mv[2], mv[3]));
    float cw[4], den = 0.f;
    #pragma unroll
    for (int p = 0; p < 4; p++) { cw[p] = __expf(mv[p] - mm) * lv[p]; den += cw[p]; }
    float inv = 1.0f / den;
    #pragma unroll
    for (int p = 0; p < 4; p++) cw[p] *= inv;

    f16x8 af[8];
    #pragma unroll
    for (int dc = 0; dc < 8; dc++) {
        float v[8] = {};
        #pragma unroll
        for (int p = 0; p < 4; p++) {
            f16x8 o = *(const f16x8*)(Opart + ((size_t)p*M_ + rowA)*256 + q4*8 + dc*32);
            #pragma unroll
            for (int j = 0; j < 8; j++) v[j] += cw[p] * (float)o[j];
        }
        f16x8 h;
        #pragma unroll
        for (int j = 0; j < 8; j++) h[j] = (f16)v[j];
        af[dc] = h;
    }

    f32x4 acc[16];
    #pragma unroll
    for (int nt = 0; nt < 16; nt++) acc[nt] = (f32x4){0.f,0.f,0.f,0.f};
    #pragma unroll
    for (int dc = 0; dc < 8; dc++) {
        #pragma unroll
        for (int nt = 0; nt < 16; nt++) {
            f16x8 bf = *(const f16x8*)(Wfch + (size_t)(nt*16 + l15)*256 + dc*32 + q4*8);
            acc[nt] = MFMA16(af[dc], bf, acc[nt]);
        }
    }
    #pragma unroll
    for (int nt = 0; nt < 16; nt++) {
        float bias = bfc[nt*16 + l15];
        #pragma unroll
        for (int r = 0; r < 4; r++)
            out[(size_t)(m0 + q4*4 + r) * 256 + nt*16 + l15] = acc[nt][r] + bias;
    }
}

// ---------------------------------------------------------------------------
extern "C" void kernel_launch(void* const* d_in, const int* in_sizes, int n_in,
                              void* d_out, int out_size, void* d_ws, size_t ws_size,
                              hipStream_t stream)
{
    const float* x   = (const float*)d_in[0];
    const float* Wq  = (const float*)d_in[1];
    const float* bq  = (const float*)d_in[2];
    const float* Wk  = (const float*)d_in[3];
    const float* bk  = (const float*)d_in[4];
    const float* Wv  = (const float*)d_in[5];
    const float* bv  = (const float*)d_in[6];
    const float* Wfc = (const float*)d_in[7];
    const float* bfc = (const float*)d_in[8];
    float* out = (float*)d_out;

    char* ws = (char*)d_ws;
    f16*   Qh    = (f16*)(ws + QH_OFF);
    f16*   Kh    = (f16*)(ws + KH_OFF);
    f16*   Vt    = (f16*)(ws + VT_OFF);
    f16*   Wfch  = (f16*)(ws + WFCH_OFF);
    f16*   Wqs   = (f16*)(ws + WQS_OFF);
    f16*   Wks   = (f16*)(ws + WKS_OFF);
    f16*   Wvs   = (f16*)(ws + WVS_OFF);
    f16*   Opart = (f16*)(ws + OP_OFF);
    float* Ml    = (float*)(ws + ML_OFF);

    cvt_w<<<dim3(64, 4), 256, 0, stream>>>(Wq, Wk, Wv, Wfc, Wqs, Wks, Wvs, Wfch);
    proj_kernel<<<dim3(256, 3), 256, 0, stream>>>(x, Wqs, Wks, Wvs, bq, bk, bv, Qh, Kh, Vt);
    attn_kernel<<<512, 256, 0, stream>>>(Qh, Kh, Vt, Opart, Ml);
    merge_fc_kernel<<<256, 256, 0, stream>>>(Opart, Ml, Wfch, bfc, out);
}

// Round 9
// 207.320 us; speedup vs baseline: 2.0653x; 1.0533x over previous
//
#include <hip/hip_runtime.h>
#include <stdint.h>

// Problem constants
#define B_ 4
#define N_ 4096
#define D_ 256
#define M_ (B_*N_)   // 16384

typedef _Float16 f16;
typedef _Float16 f16x8 __attribute__((ext_vector_type(8)));
typedef float    f32x4  __attribute__((ext_vector_type(4)));
typedef float    f32x16 __attribute__((ext_vector_type(16)));

#define MFMA16(A,B,C) __builtin_amdgcn_mfma_f32_16x16x32_f16(A,B,C,0,0,0)
#define MFMA32(A,B,C) __builtin_amdgcn_mfma_f32_32x32x16_f16(A,B,C,0,0,0)

// workspace layout (bytes)
#define QH_OFF   0u            // Qh:   16384*256*2 = 8388608
#define KH_OFF   8388608u      // Kh:   8388608 (PRE-SWIZZLED)
#define VT_OFF   16777216u     // Vt:   [4][256][4096] f16 = 8388608
#define WFCH_OFF 25165824u     // Wfch: 131072 (DMA image, 8 slabs x 16KB)
#define WQS_OFF  25296896u     // Wqs:  262144 (DMA image, hi|lo per dc-slab)
#define WKS_OFF  25559040u
#define WVS_OFF  25821184u
#define OP_OFF   26083328u     // Opart: f16 [4][16384][256] = 33554432
#define ML_OFF   59637760u     // Ml: f32 [4][16384][2] = 524288

typedef __attribute__((address_space(3))) uint32_t lds_u32;
typedef __attribute__((address_space(1))) const uint32_t g_u32;

__device__ __forceinline__ void stage16(const f16* g, f16* lbase) {
    __builtin_amdgcn_global_load_lds((g_u32*)g, (lds_u32*)lbase, 16, 0, 0);
}
__device__ __forceinline__ uint32_t pk2(float a, float b) {
    union { f16 h[2]; uint32_t u; } x;
    x.h[0] = (f16)a; x.h[1] = (f16)b;
    return x.u;
}

// ---------------------------------------------------------------------------
// Kernel 1: weight conversion.
// z<3: DMA image:  (col e, k) -> Ws[(k>>5)*16384 + t*8192 + e*32 + p*8 + (k&7)]
//   t=0 hi / 1 lo, p = ((k>>3)&3) ^ ((e>>2)&3).
// z==3 (R9): Wfc -> SAME image, single precision: 8 slabs x 8192 f16.
// ---------------------------------------------------------------------------
__global__ __launch_bounds__(256) void cvt_w(
    const float* __restrict__ Wq, const float* __restrict__ Wk,
    const float* __restrict__ Wv, const float* __restrict__ Wfc,
    f16* __restrict__ Wqs, f16* __restrict__ Wks, f16* __restrict__ Wvs,
    f16* __restrict__ Wfch)
{
    const int z = blockIdx.y;
    const float* W = (z==0) ? Wq : (z==1) ? Wk : (z==2) ? Wv : Wfc;
    int idx = (blockIdx.x * 256 + threadIdx.x) * 4;
    float4 v = *(const float4*)(W + idx);
    union { ushort4 u4; f16 h[4]; } hi, lo;
    float vv[4] = {v.x, v.y, v.z, v.w};
    #pragma unroll
    for (int j = 0; j < 4; j++) {
        hi.h[j] = (f16)vv[j];
        lo.h[j] = (f16)(vv[j] - (float)hi.h[j]);
    }
    int col = idx >> 8, k = idx & 255;
    int dc = k >> 5, c8 = (k >> 3) & 3, j = k & 7;
    int p  = c8 ^ ((col >> 2) & 3);
    if (z == 3) {
        *(ushort4*)(Wfch + dc*8192 + col*32 + p*8 + j) = hi.u4;
    } else {
        f16* Ws = (z==0) ? Wqs : (z==1) ? Wks : Wvs;
        int base = dc*16384 + col*32 + p*8 + j;
        *(ushort4*)(Ws + base)        = hi.u4;
        *(ushort4*)(Ws + base + 8192) = lo.u4;
    }
}

// ---------------------------------------------------------------------------
// Kernel 2: QKV projection (f16 MFMA hi/lo), LDS-staged B (unchanged from R8).
// ---------------------------------------------------------------------------
__global__ __launch_bounds__(256, 2) void proj_kernel(
    const float* __restrict__ x,
    const f16* __restrict__ Wqs, const f16* __restrict__ Wks,
    const f16* __restrict__ Wvs,
    const float* __restrict__ bq, const float* __restrict__ bk,
    const float* __restrict__ bv,
    f16* __restrict__ Qh, f16* __restrict__ Kh, f16* __restrict__ Vt)
{
    const int z = blockIdx.y;
    const f16*   Ws   = (z==0) ? Wqs : (z==1) ? Wks : Wvs;
    const float* bias = (z==0) ? bq  : (z==1) ? bk  : bv;

    __shared__ __align__(16) f16 Bs[2][16384];   // 64KB dbuf; VTs union below

    const int tid  = threadIdx.x;
    const int w    = tid >> 6;
    const int lane = tid & 63;
    const int l15  = lane & 15;
    const int q4   = lane >> 4;
    const int m0   = blockIdx.x * 64 + w * 16;
    const int rowA = m0 + l15;
    const int sw   = (l15 >> 2) & 3;             // B read swizzle key

    int s8[8];
    #pragma unroll
    for (int i = 0; i < 8; i++) s8[i] = (tid + i*256) * 8;

    f32x4 acc[16];
    #pragma unroll
    for (int nt = 0; nt < 16; nt++) acc[nt] = (f32x4){0.f,0.f,0.f,0.f};

    // prologue: DMA slab 0, load x chunk 0
    #pragma unroll
    for (int i = 0; i < 8; i++) stage16(Ws + s8[i], &Bs[0][0] + s8[i]);
    const float* xp = x + (size_t)rowA * 256;
    float4 a0 = *(const float4*)(xp + q4*8);
    float4 a1 = *(const float4*)(xp + q4*8 + 4);

    for (int dc = 0; dc < 8; dc++) {
        const int cur = dc & 1;
        __syncthreads();                         // drains DMA(dc); prev reads done
        if (dc < 7) {                            // DMA slab dc+1
            const f16* src = Ws + (size_t)(dc+1)*16384;
            f16* dst = &Bs[cur ^ 1][0];
            #pragma unroll
            for (int i = 0; i < 8; i++) stage16(src + s8[i], dst + s8[i]);
        }
        float av[8] = {a0.x,a0.y,a0.z,a0.w,a1.x,a1.y,a1.z,a1.w};
        f16x8 ah, alo;
        #pragma unroll
        for (int j = 0; j < 8; j++) {
            ah[j]  = (f16)av[j];
            alo[j] = (f16)(av[j] - (float)ah[j]);
        }
        if (dc < 7) {                            // prefetch next x chunk
            a0 = *(const float4*)(xp + (dc+1)*32 + q4*8);
            a1 = *(const float4*)(xp + (dc+1)*32 + q4*8 + 4);
        }
        const f16* Bc = &Bs[cur][0];
        #pragma unroll
        for (int nt = 0; nt < 16; nt++) {
            const f16* bp = Bc + (nt*16 + l15)*32 + ((q4 ^ sw) << 3);
            f16x8 bh = *(const f16x8*)bp;
            f16x8 bl = *(const f16x8*)(bp + 8192);
            acc[nt] = MFMA16(ah,  bl, acc[nt]);
            acc[nt] = MFMA16(alo, bh, acc[nt]);
            acc[nt] = MFMA16(ah,  bh, acc[nt]);
        }
    }

    if (z == 0) {
        #pragma unroll
        for (int nt = 0; nt < 16; nt++) {
            float bb = bias[nt*16 + l15];
            #pragma unroll
            for (int r = 0; r < 4; r++)
                Qh[(size_t)(m0 + q4*4 + r)*256 + nt*16 + l15] = (f16)(acc[nt][r] + bb);
        }
    } else if (z == 1) {
        // swizzled Kh image for attn's DMA staging
        const int cbase = (l15 >> 3);
        const int j     = l15 & 7;
        #pragma unroll
        for (int nt = 0; nt < 16; nt++) {
            float bb = bias[nt*16 + l15];
            int c = nt*2 + cbase;
            #pragma unroll
            for (int r = 0; r < 4; r++) {
                int m = m0 + q4*4 + r;
                Kh[(size_t)m*256 + (size_t)((c ^ (m & 7)) << 3) + j] = (f16)(acc[nt][r] + bb);
            }
        }
    } else {
        // V: transpose through LDS (unions with Bs), coalesced b128 stores
        uint32_t* VTs = (uint32_t*)&Bs[0][0];
        const int bb_ = m0 >> 12;
        const int n0  = (blockIdx.x * 64) & 4095;
        const int mloc = w*16 + q4*4;
        const int mc   = mloc >> 3;
        __syncthreads();
        #pragma unroll
        for (int nt = 0; nt < 16; nt++) {
            int e = nt*16 + l15;
            float bv_ = bias[e];
            uint32_t w0 = pk2(acc[nt][0]+bv_, acc[nt][1]+bv_);
            uint32_t w1 = pk2(acc[nt][2]+bv_, acc[nt][3]+bv_);
            int base = e*36 + ((mc ^ (e & 7)) << 2) + ((q4*2) & 3);
            VTs[base]     = w0;
            VTs[base + 1] = w1;
        }
        __syncthreads();
        #pragma unroll
        for (int i = 0; i < 8; i++) {
            int e  = w*64 + i*8 + (lane >> 3);
            int nc = lane & 7;
            const f16* src = (const f16*)&VTs[e*36 + ((nc ^ (e & 7)) << 2)];
            f16x8 v = *(const f16x8*)src;
            *(f16x8*)(Vt + ((size_t)bb_*256 + e)*4096 + n0 + nc*8) = v;
        }
    }
}

// ---------------------------------------------------------------------------
// Kernel 3: flash attention, TRANSPOSED compute with 32x32x16 MFMA.
// (unchanged from R7/R8 — verified)
// ---------------------------------------------------------------------------
#define MARGIN 10.0f
__global__ __launch_bounds__(256, 2) void attn_kernel(
    const f16* __restrict__ Qh, const f16* __restrict__ Kh,
    const f16* __restrict__ Vt,
    f16* __restrict__ Opart, float* __restrict__ Ml)
{
    __shared__ __align__(16) f16 SMEM[32768];     // Ks[2][8192] | Vs[2][8192]
    f16* Ks = SMEM;
    f16* Vs = SMEM + 16384;

    const int combo = blockIdx.x & 15;
    const int b   = combo >> 2;
    const int sp  = combo & 3;
    const int qt  = blockIdx.x >> 4;              // 0..31
    const int tid  = threadIdx.x;
    const int w    = tid >> 6;
    const int lane = tid & 63;
    const int l31  = lane & 31;                   // q column
    const int half = lane >> 5;
    const int qbase = qt * 128 + w * 32;          // wave's q-row base (incl. w)
    const int vx   = (l31 >> 2) & 3;              // V image swizzle key

    // Q as B-frags (16 steps of d): lane holds Q[q][8d]
    f16x8 qf[16];
    {
        const f16* qp = Qh + ((size_t)(b*4096 + qbase + l31))*256 + half*8;
        #pragma unroll
        for (int st = 0; st < 16; st++) qf[st] = *(const f16x8*)(qp + st*16);
    }

    f32x16 Oa[8];                                 // O^T d-tiles (C-layout)
    #pragma unroll
    for (int t = 0; t < 8; t++)
        #pragma unroll
        for (int r = 0; r < 16; r++) Oa[t][r] = 0.f;
    float mo = -3e38f, ls = 0.f;                  // per-lane (q = l31)

    const f16* kg0 = Kh + ((size_t)(b*4096 + sp*1024)) * 256;   // swizzled
    const f16* vg0 = Vt + ((size_t)b*256) * 4096 + sp*1024;

    int kslot[4], voff[4];
    #pragma unroll
    for (int i = 0; i < 4; i++) {
        int s = tid + i*256;
        kslot[i] = s * 8;
        int d = s >> 2;
        int kc = (s & 3) ^ ((s >> 4) & 3);        // image: pos = kc ^ ((d>>2)&3)
        voff[i] = d * 4096 + kc * 8;
    }

    // prologue: DMA K(0)
    #pragma unroll
    for (int i = 0; i < 4; i++) stage16(kg0 + kslot[i], Ks + kslot[i]);

    f16x8 bp0, bp1;                               // carried P^T B-frags

    for (int it = 0; it < 32; it++) {
        const int cur = it & 1;
        __syncthreads();                          // drains K(t), V(t-1) DMAs
        if (it + 1 < 32) {
            const f16* kg = kg0 + (size_t)(it+1) * 8192;
            f16* kl = Ks + (cur ^ 1) * 8192;
            #pragma unroll
            for (int i = 0; i < 4; i++) stage16(kg + kslot[i], kl + kslot[i]);
        }
        {
            const f16* vg = vg0 + it*32;
            f16* vl = Vs + cur * 8192;
            #pragma unroll
            for (int i = 0; i < 4; i++) stage16(vg + voff[i], vl + kslot[i]);
        }

        // S^T(t) interleaved with PV(t-1): 32 MFMAs
        const f16* krp = Ks + cur*8192 + l31*256;
        const f16* vpp = Vs + (cur^1)*8192 + l31*32;
        f32x16 sa;
        #pragma unroll
        for (int r = 0; r < 16; r++) sa[r] = 0.f;
        if (it > 0) {
            #pragma unroll
            for (int st = 0; st < 16; st++) {
                f16x8 ka = *(const f16x8*)(krp + (((st*2 + half) ^ (lane & 7)) << 3));
                sa = MFMA32(ka, qf[st], sa);
                int t = st >> 1, kh = st & 1;
                f16x8 va = *(const f16x8*)(vpp + t*1024 + (((half + kh*2) ^ vx) << 3));
                Oa[t] = MFMA32(va, kh ? bp1 : bp0, Oa[t]);
            }
        } else {
            #pragma unroll
            for (int st = 0; st < 16; st++) {
                f16x8 ka = *(const f16x8*)(krp + (((st*2 + half) ^ (lane & 7)) << 3));
                sa = MFMA32(ka, qf[st], sa);
            }
        }

        // per-lane hysteresis softmax (q = lane col)
        float tm = sa[0];
        #pragma unroll
        for (int r = 1; r < 16; r++) tm = fmaxf(tm, sa[r]);
        if (__any(tm > mo + MARGIN)) {
            float tmq = fmaxf(tm, __shfl_xor(tm, 32));
            float mn = fmaxf(mo, tmq);
            float al = __expf(mo - mn);
            mo = mn; ls *= al;
            #pragma unroll
            for (int t = 0; t < 8; t++)
                #pragma unroll
                for (int r = 0; r < 16; r++) Oa[t][r] *= al;
        }
        float p[16];
        #pragma unroll
        for (int r = 0; r < 16; r++) { p[r] = __expf(sa[r] - mo); ls += p[r]; }

        // build P^T B-frags: keys 16kh + [0..7](h=0) / [8..15](h=1)
        #pragma unroll
        for (int kh = 0; kh < 2; kh++) {
            uint32_t lo0 = pk2(p[8*kh+0], p[8*kh+1]);
            uint32_t lo1 = pk2(p[8*kh+2], p[8*kh+3]);
            uint32_t hi0 = pk2(p[8*kh+4], p[8*kh+5]);
            uint32_t hi1 = pk2(p[8*kh+6], p[8*kh+7]);
            uint32_t s0 = half ? lo0 : hi0;
            uint32_t s1 = half ? lo1 : hi1;
            uint32_t r0 = __shfl_xor(s0, 32);
            uint32_t r1 = __shfl_xor(s1, 32);
            uint32_t k0 = half ? hi0 : lo0;
            uint32_t k1 = half ? hi1 : lo1;
            union { uint32_t u[4]; f16x8 v; } bb;
            bb.u[0] = half ? r0 : k0;
            bb.u[1] = half ? r1 : k1;
            bb.u[2] = half ? k0 : r0;
            bb.u[3] = half ? k1 : r1;
            if (kh == 0) bp0 = bb.v; else bp1 = bb.v;
        }
    }

    // final PV(31): drain V(31) DMA, then consume
    __syncthreads();
    {
        const f16* vpp = Vs + 8192 + l31*32;      // V(31) in Vs[1]
        #pragma unroll
        for (int t = 0; t < 8; t++) {
            #pragma unroll
            for (int kh = 0; kh < 2; kh++) {
                f16x8 va = *(const f16x8*)(vpp + t*1024 + (((half + kh*2) ^ vx) << 3));
                Oa[t] = MFMA32(va, kh ? bp1 : bp0, Oa[t]);
            }
        }
    }
    __syncthreads();                              // all waves done with SMEM tiles

    // epilogue: l across half-pair, normalize, un-transpose via per-wave LDS
    float l = ls + __shfl_xor(ls, 32);
    float inv = 1.0f / l;
    f16* tb = SMEM + w * 8192;                    // 16KB per wave
    #pragma unroll
    for (int t = 0; t < 8; t++) {
        #pragma unroll
        for (int rp = 0; rp < 8; rp++) {
            int r0 = rp * 2;
            int d  = (r0 & 3) + 8*(r0 >> 2) + 4*half + t*32;
            int c  = d >> 3, j = d & 7;
            uint32_t wv = pk2(Oa[t][r0]*inv, Oa[t][r0+1]*inv);
            *(uint32_t*)(tb + l31*256 + ((c ^ (l31 & 7)) << 3) + (j & 6)) = wv;
        }
    }
    // coalesced read-back + global store (per-wave region, rows = qbase+q)
    f16* opb = Opart + ((size_t)sp*M_ + b*4096 + qbase) * 256;
    #pragma unroll
    for (int i = 0; i < 16; i++) {
        int q = (i & 3)*8 + (lane >> 3);
        int c = (i >> 2)*8 + (lane & 7);
        f16x8 v = *(const f16x8*)(tb + q*256 + ((c ^ (q & 7)) << 3));
        *(f16x8*)(opb + (size_t)q*256 + c*8) = v;
    }
    if (half == 0) {
        size_t mrow = (size_t)sp*M_ + b*4096 + qbase + l31;
        Ml[mrow*2]     = mo;
        Ml[mrow*2 + 1] = l;
    }
}

// ---------------------------------------------------------------------------
// Kernel 4: merge 4 normalized k-quarter partials + FC + bias.
// R9: Wfc B-frags staged via global_load_lds double-buffered LDS (was
// per-MFMA global loads -> latency-bound ~70us, same pathology as R7 proj).
// Opart fragments prefetched one dc ahead.
// ---------------------------------------------------------------------------
__global__ __launch_bounds__(256, 2) void merge_fc_kernel(
    const f16* __restrict__ Opart, const float* __restrict__ Ml,
    const f16* __restrict__ Wfci, const float* __restrict__ bfc,
    float* __restrict__ out)
{
    __shared__ __align__(16) f16 Bs[2][8192];    // 2 x 16KB slabs

    const int tid  = threadIdx.x;
    const int w    = tid >> 6;
    const int lane = tid & 63;
    const int l15  = lane & 15;
    const int q4   = lane >> 4;
    const int m0   = blockIdx.x * 64 + w * 16;
    const int rowA = m0 + l15;
    const int sw   = (l15 >> 2) & 3;             // B read swizzle key

    int s4[4];
    #pragma unroll
    for (int i = 0; i < 4; i++) s4[i] = (tid + i*256) * 8;

    float mv[4], lv[4];
    #pragma unroll
    for (int p = 0; p < 4; p++) {
        mv[p] = Ml[((size_t)p*M_ + rowA)*2];
        lv[p] = Ml[((size_t)p*M_ + rowA)*2 + 1];
    }
    float mm = fmaxf(fmaxf(mv[0], mv[1]), fmaxf(mv[2], mv[3]));
    float cw[4], den = 0.f;
    #pragma unroll
    for (int p = 0; p < 4; p++) { cw[p] = __expf(mv[p] - mm) * lv[p]; den += cw[p]; }
    float invd = 1.0f / den;
    #pragma unroll
    for (int p = 0; p < 4; p++) cw[p] *= invd;

    // prologue: DMA slab 0, prefetch Opart frags for dc=0
    #pragma unroll
    for (int i = 0; i < 4; i++) stage16(Wfci + s4[i], &Bs[0][0] + s4[i]);
    const f16* opb = Opart + (size_t)rowA*256 + q4*8;
    f16x8 of[4];
    #pragma unroll
    for (int p = 0; p < 4; p++) of[p] = *(const f16x8*)(opb + (size_t)p*M_*256);

    f32x4 acc[16];
    #pragma unroll
    for (int nt = 0; nt < 16; nt++) acc[nt] = (f32x4){0.f,0.f,0.f,0.f};

    for (int dc = 0; dc < 8; dc++) {
        const int cur = dc & 1;
        __syncthreads();                         // drains DMA(dc); prev reads done
        if (dc < 7) {
            const f16* src = Wfci + (size_t)(dc+1)*8192;
            f16* dst = &Bs[cur ^ 1][0];
            #pragma unroll
            for (int i = 0; i < 4; i++) stage16(src + s4[i], dst + s4[i]);
        }
        // weighted merge of the 4 partials -> A-frag
        float v[8] = {};
        #pragma unroll
        for (int p = 0; p < 4; p++)
            #pragma unroll
            for (int j = 0; j < 8; j++) v[j] += cw[p] * (float)of[p][j];
        f16x8 af;
        #pragma unroll
        for (int j = 0; j < 8; j++) af[j] = (f16)v[j];
        if (dc < 7) {                            // prefetch next Opart frags
            #pragma unroll
            for (int p = 0; p < 4; p++)
                of[p] = *(const f16x8*)(opb + (size_t)p*M_*256 + (dc+1)*32);
        }
        const f16* Bc = &Bs[cur][0];
        #pragma unroll
        for (int nt = 0; nt < 16; nt++) {
            f16x8 bf = *(const f16x8*)(Bc + (nt*16 + l15)*32 + ((q4 ^ sw) << 3));
            acc[nt] = MFMA16(af, bf, acc[nt]);
        }
    }
    #pragma unroll
    for (int nt = 0; nt < 16; nt++) {
        float bias = bfc[nt*16 + l15];
        #pragma unroll
        for (int r = 0; r < 4; r++)
            out[(size_t)(m0 + q4*4 + r) * 256 + nt*16 + l15] = acc[nt][r] + bias;
    }
}

// ---------------------------------------------------------------------------
extern "C" void kernel_launch(void* const* d_in, const int* in_sizes, int n_in,
                              void* d_out, int out_size, void* d_ws, size_t ws_size,
                              hipStream_t stream)
{
    const float* x   = (const float*)d_in[0];
    const float* Wq  = (const float*)d_in[1];
    const float* bq  = (const float*)d_in[2];
    const float* Wk  = (const float*)d_in[3];
    const float* bk  = (const float*)d_in[4];
    const float* Wv  = (const float*)d_in[5];
    const float* bv  = (const float*)d_in[6];
    const float* Wfc = (const float*)d_in[7];
    const float* bfc = (const float*)d_in[8];
    float* out = (float*)d_out;

    char* ws = (char*)d_ws;
    f16*   Qh    = (f16*)(ws + QH_OFF);
    f16*   Kh    = (f16*)(ws + KH_OFF);
    f16*   Vt    = (f16*)(ws + VT_OFF);
    f16*   Wfch  = (f16*)(ws + WFCH_OFF);
    f16*   Wqs   = (f16*)(ws + WQS_OFF);
    f16*   Wks   = (f16*)(ws + WKS_OFF);
    f16*   Wvs   = (f16*)(ws + WVS_OFF);
    f16*   Opart = (f16*)(ws + OP_OFF);
    float* Ml    = (float*)(ws + ML_OFF);

    cvt_w<<<dim3(64, 4), 256, 0, stream>>>(Wq, Wk, Wv, Wfc, Wqs, Wks, Wvs, Wfch);
    proj_kernel<<<dim3(256, 3), 256, 0, stream>>>(x, Wqs, Wks, Wvs, bq, bk, bv, Qh, Kh, Vt);
    attn_kernel<<<512, 256, 0, stream>>>(Qh, Kh, Vt, Opart, Ml);
    merge_fc_kernel<<<256, 256, 0, stream>>>(Opart, Ml, Wfch, bfc, out);
}